// Round 1
// baseline (5671.886 us; speedup 1.0000x reference)
//
#include <hip/hip_runtime.h>

#define S 2048
#define D 2048
#define H 16
#define HD 128
#define N3 6144  // 3*D

// ---------------------------------------------------------------------------
// Tiled f32 GEMM (64x64 tile, BK=16, 256 threads, 4x4 micro-tile) for
// qkv = x @ Wqkv + bqkv, with fused RoPE + scatter epilogue:
//   col j -> which = j/2048 (0=q,1=k,2=v), h = (j%2048)/128, d = j%128
//   q,k get RoPE (freqs indexed by row); k,v scattered to input_pos[row].
// Layouts out: qb/kb/vb are [H, S, HD].
// ---------------------------------------------------------------------------
__global__ __launch_bounds__(256) void gemm_qkv_kernel(
    const float* __restrict__ x, const float* __restrict__ W,
    const float* __restrict__ bias, const float* __restrict__ freqs,
    const int* __restrict__ input_pos,
    float* __restrict__ qb, float* __restrict__ kb, float* __restrict__ vb)
{
    __shared__ float As[16][68];   // [k][m], padded: 68*4=272B keeps 16B align + bank spread
    __shared__ float Bs[16][64];   // [k][n]
    const int bx = blockIdx.x;     // over N3/64 = 96
    const int by = blockIdx.y;     // over S/64  = 32
    const int tid = threadIdx.x;
    const int tx = tid & 15, ty = tid >> 4;
    const int row0 = by * 64, col0 = bx * 64;

    const int am = tid >> 2;            // 0..63  (A row within tile)
    const int ak = (tid & 3) * 4;       // 0,4,8,12
    const int bk = tid >> 4;            // 0..15
    const int bn = (tid & 15) * 4;      // 0..60

    float acc[4][4] = {};

    for (int k0 = 0; k0 < D; k0 += 16) {
        float4 av = *(const float4*)&x[(size_t)(row0 + am) * D + k0 + ak];
        float4 bv = *(const float4*)&W[(size_t)(k0 + bk) * N3 + col0 + bn];
        __syncthreads();  // previous compute done before overwrite
        As[ak + 0][am] = av.x; As[ak + 1][am] = av.y;
        As[ak + 2][am] = av.z; As[ak + 3][am] = av.w;
        *(float4*)&Bs[bk][bn] = bv;
        __syncthreads();
        #pragma unroll
        for (int k = 0; k < 16; k++) {
            float4 a4 = *(const float4*)&As[k][ty * 4];
            float4 b4 = *(const float4*)&Bs[k][tx * 4];
            float a[4] = {a4.x, a4.y, a4.z, a4.w};
            float b[4] = {b4.x, b4.y, b4.z, b4.w};
            #pragma unroll
            for (int r = 0; r < 4; r++)
                #pragma unroll
                for (int c = 0; c < 4; c++)
                    acc[r][c] += a[r] * b[c];
        }
    }

    // epilogue: bias + RoPE + scatter
    const int j0 = col0 + tx * 4;          // aligned to 4; never crosses head or q/k/v boundary
    const int which = j0 >> 11;            // 0=q, 1=k, 2=v
    const int hh = (j0 & 2047) >> 7;
    const int d0 = j0 & 127;
    const float bv0 = bias[j0 + 0], bv1 = bias[j0 + 1];
    const float bv2 = bias[j0 + 2], bv3 = bias[j0 + 3];
    #pragma unroll
    for (int r = 0; r < 4; r++) {
        const int grow = row0 + ty * 4 + r;
        float v0 = acc[r][0] + bv0, v1 = acc[r][1] + bv1;
        float v2 = acc[r][2] + bv2, v3 = acc[r][3] + bv3;
        if (which == 2) {
            const int pos = input_pos[grow];
            float4 o4 = make_float4(v0, v1, v2, v3);
            *(float4*)&vb[((size_t)hh * S + pos) * HD + d0] = o4;
        } else {
            const float* fc = &freqs[((size_t)grow * 64 + (d0 >> 1)) * 2];
            float c0 = fc[0], s0 = fc[1], c1 = fc[2], s1 = fc[3];
            float o0 = v0 * c0 - v1 * s0, o1 = v1 * c0 + v0 * s0;
            float o2 = v2 * c1 - v3 * s1, o3 = v3 * c1 + v2 * s1;
            float4 o4 = make_float4(o0, o1, o2, o3);
            if (which == 0) {
                *(float4*)&qb[((size_t)hh * S + grow) * HD + d0] = o4;
            } else {
                const int pos = input_pos[grow];
                *(float4*)&kb[((size_t)hh * S + pos) * HD + d0] = o4;
            }
        }
    }
}

// ---------------------------------------------------------------------------
// Causal flash attention, one block (128 threads) per (query row, head).
// Online softmax over 32-key tiles staged in LDS. ctx layout [S, H, HD]
// == [S, D] row-major for the dense GEMM.
// ---------------------------------------------------------------------------
#define TK 32
__global__ __launch_bounds__(128) void attn_kernel(
    const float* __restrict__ qb, const float* __restrict__ kb,
    const float* __restrict__ vb, float* __restrict__ ctx)
{
    const int qi = blockIdx.x;   // 0..S-1
    const int h  = blockIdx.y;   // 0..H-1
    const int t  = threadIdx.x;  // 0..127 (owns output dim t)

    __shared__ float qs[HD];
    __shared__ float Ks[TK * HD];
    __shared__ float Vs[TK * HD];
    __shared__ float ss[TK];
    __shared__ float ps[TK];

    qs[t] = qb[((size_t)h * S + qi) * HD + t];
    float o = 0.f, m = -1e30f, l = 0.f;
    const float scale = 0.08838834764831845f;  // 1/sqrt(128)
    const int nkeys = qi + 1;
    __syncthreads();

    for (int k0 = 0; k0 < nkeys; k0 += TK) {
        const int nk = min(TK, nkeys - k0);
        // stage K,V tile (coalesced)
        for (int idx = t; idx < nk * HD; idx += 128) {
            Ks[idx] = kb[((size_t)h * S + k0) * HD + idx];
            Vs[idx] = vb[((size_t)h * S + k0) * HD + idx];
        }
        __syncthreads();
        // scores: 4 threads per key, 32 dims each, shuffle-reduce
        const int jj = t >> 2, part = t & 3;
        float partial = 0.f;
        if (jj < nk) {
            const float* krow = &Ks[jj * HD + part * 32];
            const float* qrow = &qs[part * 32];
            #pragma unroll
            for (int d = 0; d < 32; d++) partial += qrow[d] * krow[d];
        }
        partial += __shfl_down(partial, 2);
        partial += __shfl_down(partial, 1);
        if (part == 0 && jj < nk) ss[jj] = partial * scale;
        __syncthreads();
        // softmax stats (replicated per-thread from LDS broadcast)
        float tmax = -1e30f;
        for (int j = 0; j < nk; j++) tmax = fmaxf(tmax, ss[j]);
        const float newm = fmaxf(m, tmax);
        const float alpha = __expf(m - newm);
        if (t < nk) ps[t] = __expf(ss[t] - newm);
        __syncthreads();
        float tsum = 0.f, oacc = 0.f;
        for (int j = 0; j < nk; j++) {
            const float p = ps[j];
            tsum += p;
            oacc += p * Vs[j * HD + t];
        }
        l = l * alpha + tsum;
        o = o * alpha + oacc;
        m = newm;
        __syncthreads();  // protect Ks/Vs/ss/ps before next tile's load
    }
    ctx[((size_t)qi * H + h) * HD + t] = o / l;
}

// ---------------------------------------------------------------------------
// Dense output GEMM: out = ctx @ Wdense + bdense  (2048 x 2048 x 2048)
// ---------------------------------------------------------------------------
__global__ __launch_bounds__(256) void gemm_dense_kernel(
    const float* __restrict__ A, const float* __restrict__ W,
    const float* __restrict__ bias, float* __restrict__ out)
{
    __shared__ float As[16][68];
    __shared__ float Bs[16][64];
    const int bx = blockIdx.x;   // over D/64 = 32
    const int by = blockIdx.y;   // over S/64 = 32
    const int tid = threadIdx.x;
    const int tx = tid & 15, ty = tid >> 4;
    const int row0 = by * 64, col0 = bx * 64;

    const int am = tid >> 2;
    const int ak = (tid & 3) * 4;
    const int bk = tid >> 4;
    const int bn = (tid & 15) * 4;

    float acc[4][4] = {};

    for (int k0 = 0; k0 < D; k0 += 16) {
        float4 av = *(const float4*)&A[(size_t)(row0 + am) * D + k0 + ak];
        float4 bv = *(const float4*)&W[(size_t)(k0 + bk) * D + col0 + bn];
        __syncthreads();
        As[ak + 0][am] = av.x; As[ak + 1][am] = av.y;
        As[ak + 2][am] = av.z; As[ak + 3][am] = av.w;
        *(float4*)&Bs[bk][bn] = bv;
        __syncthreads();
        #pragma unroll
        for (int k = 0; k < 16; k++) {
            float4 a4 = *(const float4*)&As[k][ty * 4];
            float4 b4 = *(const float4*)&Bs[k][tx * 4];
            float a[4] = {a4.x, a4.y, a4.z, a4.w};
            float b[4] = {b4.x, b4.y, b4.z, b4.w};
            #pragma unroll
            for (int r = 0; r < 4; r++)
                #pragma unroll
                for (int c = 0; c < 4; c++)
                    acc[r][c] += a[r] * b[c];
        }
    }

    const int j0 = col0 + tx * 4;
    const float bv0 = bias[j0 + 0], bv1 = bias[j0 + 1];
    const float bv2 = bias[j0 + 2], bv3 = bias[j0 + 3];
    #pragma unroll
    for (int r = 0; r < 4; r++) {
        const int grow = row0 + ty * 4 + r;
        float4 o4 = make_float4(acc[r][0] + bv0, acc[r][1] + bv1,
                                acc[r][2] + bv2, acc[r][3] + bv3);
        *(float4*)&out[(size_t)grow * D + j0] = o4;
    }
}

extern "C" void kernel_launch(void* const* d_in, const int* in_sizes, int n_in,
                              void* d_out, int out_size, void* d_ws, size_t ws_size,
                              hipStream_t stream) {
    const float* x      = (const float*)d_in[0];
    const float* freqs  = (const float*)d_in[1];
    const int*   pos    = (const int*)d_in[2];
    const float* Wqkv   = (const float*)d_in[3];
    const float* bqkv   = (const float*)d_in[4];
    const float* Wdense = (const float*)d_in[5];
    const float* bdense = (const float*)d_in[6];
    float* out = (float*)d_out;

    // workspace: q, k, v [H,S,HD] + ctx [S,D]  -> 4 * 16 MB = 64 MB
    float* qb  = (float*)d_ws;
    float* kb  = qb + (size_t)H * S * HD;
    float* vb  = kb + (size_t)H * S * HD;
    float* ctx = vb + (size_t)H * S * HD;

    dim3 g1(N3 / 64, S / 64);
    gemm_qkv_kernel<<<g1, 256, 0, stream>>>(x, Wqkv, bqkv, freqs, pos, qb, kb, vb);

    dim3 g2(S, H);
    attn_kernel<<<g2, 128, 0, stream>>>(qb, kb, vb, ctx);

    dim3 g3(D / 64, S / 64);
    gemm_dense_kernel<<<g3, 256, 0, stream>>>(ctx, Wdense, bdense, out);
}

// Round 2
// 1557.443 us; speedup vs baseline: 3.6418x; 3.6418x over previous
//
#include <hip/hip_runtime.h>

#define S 2048
#define D 2048
#define H 16
#define HD 128
#define N3 6144  // 3*D

// ---------------------------------------------------------------------------
// QKV GEMM (unchanged from R1 — measured ~83% of f32 vector peak together
// with the dense GEMM). Fused bias + RoPE + scatter epilogue.
// ---------------------------------------------------------------------------
__global__ __launch_bounds__(256) void gemm_qkv_kernel(
    const float* __restrict__ x, const float* __restrict__ W,
    const float* __restrict__ bias, const float* __restrict__ freqs,
    const int* __restrict__ input_pos,
    float* __restrict__ qb, float* __restrict__ kb, float* __restrict__ vb)
{
    __shared__ float As[16][68];
    __shared__ float Bs[16][64];
    const int bx = blockIdx.x;
    const int by = blockIdx.y;
    const int tid = threadIdx.x;
    const int tx = tid & 15, ty = tid >> 4;
    const int row0 = by * 64, col0 = bx * 64;

    const int am = tid >> 2;
    const int ak = (tid & 3) * 4;
    const int bk = tid >> 4;
    const int bn = (tid & 15) * 4;

    float acc[4][4] = {};

    for (int k0 = 0; k0 < D; k0 += 16) {
        float4 av = *(const float4*)&x[(size_t)(row0 + am) * D + k0 + ak];
        float4 bv = *(const float4*)&W[(size_t)(k0 + bk) * N3 + col0 + bn];
        __syncthreads();
        As[ak + 0][am] = av.x; As[ak + 1][am] = av.y;
        As[ak + 2][am] = av.z; As[ak + 3][am] = av.w;
        *(float4*)&Bs[bk][bn] = bv;
        __syncthreads();
        #pragma unroll
        for (int k = 0; k < 16; k++) {
            float4 a4 = *(const float4*)&As[k][ty * 4];
            float4 b4 = *(const float4*)&Bs[k][tx * 4];
            float a[4] = {a4.x, a4.y, a4.z, a4.w};
            float b[4] = {b4.x, b4.y, b4.z, b4.w};
            #pragma unroll
            for (int r = 0; r < 4; r++)
                #pragma unroll
                for (int c = 0; c < 4; c++)
                    acc[r][c] += a[r] * b[c];
        }
    }

    const int j0 = col0 + tx * 4;
    const int which = j0 >> 11;
    const int hh = (j0 & 2047) >> 7;
    const int d0 = j0 & 127;
    const float bv0 = bias[j0 + 0], bv1 = bias[j0 + 1];
    const float bv2 = bias[j0 + 2], bv3 = bias[j0 + 3];
    #pragma unroll
    for (int r = 0; r < 4; r++) {
        const int grow = row0 + ty * 4 + r;
        float v0 = acc[r][0] + bv0, v1 = acc[r][1] + bv1;
        float v2 = acc[r][2] + bv2, v3 = acc[r][3] + bv3;
        if (which == 2) {
            const int pos = input_pos[grow];
            float4 o4 = make_float4(v0, v1, v2, v3);
            *(float4*)&vb[((size_t)hh * S + pos) * HD + d0] = o4;
        } else {
            const float* fc = &freqs[((size_t)grow * 64 + (d0 >> 1)) * 2];
            float c0 = fc[0], s0 = fc[1], c1 = fc[2], s1 = fc[3];
            float o0 = v0 * c0 - v1 * s0, o1 = v1 * c0 + v0 * s0;
            float o2 = v2 * c1 - v3 * s1, o3 = v3 * c1 + v2 * s1;
            float4 o4 = make_float4(o0, o1, o2, o3);
            if (which == 0) {
                *(float4*)&qb[((size_t)hh * S + grow) * HD + d0] = o4;
            } else {
                const int pos = input_pos[grow];
                *(float4*)&kb[((size_t)hh * S + pos) * HD + d0] = o4;
            }
        }
    }
}

// ---------------------------------------------------------------------------
// Flash attention, GEMM-shaped. BQ=64 query rows x BK=32 key tile, 256
// threads. All tiles row-major in LDS (d-chunked float4 dot-products make
// Q/K reads broadcast-heavy, no transpose staging). Score micro-tile 4x2,
// PV micro-tile 4x8; softmax stats in registers (score threads and PV
// threads own the same 4 query rows; reduce across tx via shfl width 16).
// K and V share one LDS buffer; V is register-prefetched during scores,
// next K during PV. Causal load balance: block handles q-tiles (r, 31-r)
// -> exactly 68 key-tiles per block; grid 16 pairs x 16 heads = 256 blocks.
// ---------------------------------------------------------------------------
#define BQ 64
#define BK 32
#define QSTR 132   // 128 + 4 pad (float4-aligned)
#define KVSTR 132
#define PSTR 68    // 64 + 4 pad

__global__ __launch_bounds__(256) void attn_kernel(
    const float* __restrict__ qb, const float* __restrict__ kb,
    const float* __restrict__ vb, float* __restrict__ ctx)
{
    __shared__ float Qs[BQ * QSTR];   // 33.8 KB
    __shared__ float KV[BK * KVSTR];  // 16.9 KB (K, then V, alternately)
    __shared__ float Ps[BK * PSTR];   // 8.7 KB   total ~59.4 KB

    const int pa = blockIdx.x;   // 0..15 (pair index)
    const int h  = blockIdx.y;   // 0..15
    const int t  = threadIdx.x;
    const int ty = t >> 4, tx = t & 15;
    const int i0  = ty * 4;      // 4 query rows owned by this thread
    const int j0  = tx * 2;      // 2 key cols in score stage
    const int dd0 = tx * 8;      // 8 output dims in PV stage
    const int lr = t >> 3;       // 0..31: load row
    const int lc = (t & 7) * 4;  // load col base (float4)

    const float* kbase = kb + (size_t)h * S * HD;
    const float* vbase = vb + (size_t)h * S * HD;
    const float kSc = 0.08838834764831845f * 1.4426950408889634f; // scale*log2e

    for (int ph = 0; ph < 2; ph++) {
        const int r = (ph == 0) ? pa : 31 - pa;
        const int q0 = r * BQ;
        const int ntiles = 2 * r + 2;

        // Q tile -> LDS (row-major)
        #pragma unroll
        for (int pp = 0; pp < 2; pp++) {
            const int iq = lr + pp * 32;
            const float* src = qb + ((size_t)h * S + q0 + iq) * HD;
            #pragma unroll
            for (int ch = 0; ch < 4; ch++)
                *(float4*)&Qs[iq * QSTR + lc + ch * 32] =
                    *(const float4*)&src[lc + ch * 32];
        }

        float O[4][8] = {};
        float m[4], l[4];
        #pragma unroll
        for (int rr = 0; rr < 4; rr++) { m[rr] = -1e30f; l[rr] = 0.f; }

        // prefetch K tile 0 into registers
        float4 kpref[4];
        #pragma unroll
        for (int ch = 0; ch < 4; ch++)
            kpref[ch] = *(const float4*)&kbase[(size_t)lr * HD + lc + ch * 32];

        __syncthreads();  // Qs ready; prev-phase compute done

        for (int kt = 0; kt < ntiles; kt++) {
            const int k0 = kt * BK;

            // K prefetch regs -> LDS (KV buffer free per loop-tail barrier)
            #pragma unroll
            for (int ch = 0; ch < 4; ch++)
                *(float4*)&KV[lr * KVSTR + lc + ch * 32] = kpref[ch];
            __syncthreads();  // K visible

            // prefetch V tile (consumed after the scores barrier)
            float4 vpref[4];
            #pragma unroll
            for (int ch = 0; ch < 4; ch++)
                vpref[ch] = *(const float4*)&vbase[(size_t)(k0 + lr) * HD + lc + ch * 32];

            // ---- scores: acc[rr][cc] = sum_d Q[i0+rr][d] * K[j0+cc][d]
            float acc[4][2] = {};
            #pragma unroll 4
            for (int d0 = 0; d0 < HD; d0 += 4) {
                float4 ka = *(const float4*)&KV[(j0 + 0) * KVSTR + d0];
                float4 kb4 = *(const float4*)&KV[(j0 + 1) * KVSTR + d0];
                #pragma unroll
                for (int rr = 0; rr < 4; rr++) {
                    float4 q4 = *(const float4*)&Qs[(i0 + rr) * QSTR + d0];
                    acc[rr][0] += q4.x * ka.x + q4.y * ka.y + q4.z * ka.z + q4.w * ka.w;
                    acc[rr][1] += q4.x * kb4.x + q4.y * kb4.y + q4.z * kb4.z + q4.w * kb4.w;
                }
            }

            // ---- mask + online softmax (stats in registers, reduce over tx)
            const bool need_mask = (k0 + BK - 1) > q0;
            float p[4][2], alpha[4];
            #pragma unroll
            for (int rr = 0; rr < 4; rr++) {
                float z0 = acc[rr][0] * kSc;
                float z1 = acc[rr][1] * kSc;
                if (need_mask) {
                    if (k0 + j0 + 0 > q0 + i0 + rr) z0 = -1e30f;
                    if (k0 + j0 + 1 > q0 + i0 + rr) z1 = -1e30f;
                }
                float rmax = fmaxf(z0, z1);
                #pragma unroll
                for (int off = 1; off < 16; off <<= 1)
                    rmax = fmaxf(rmax, __shfl_xor(rmax, off, 16));
                const float nm = fmaxf(m[rr], rmax);
                alpha[rr] = exp2f(m[rr] - nm);
                p[rr][0] = exp2f(z0 - nm);
                p[rr][1] = exp2f(z1 - nm);
                float ts = p[rr][0] + p[rr][1];
                #pragma unroll
                for (int off = 1; off < 16; off <<= 1)
                    ts += __shfl_xor(ts, off, 16);
                l[rr] = l[rr] * alpha[rr] + ts;
                m[rr] = nm;
            }
            __syncthreads();  // scores done reading K -> KV free for V

            // V regs -> LDS; P -> LDS (transposed: Ps[j][i]); next-K prefetch
            #pragma unroll
            for (int ch = 0; ch < 4; ch++)
                *(float4*)&KV[lr * KVSTR + lc + ch * 32] = vpref[ch];
            *(float4*)&Ps[(j0 + 0) * PSTR + i0] =
                make_float4(p[0][0], p[1][0], p[2][0], p[3][0]);
            *(float4*)&Ps[(j0 + 1) * PSTR + i0] =
                make_float4(p[0][1], p[1][1], p[2][1], p[3][1]);
            if (kt + 1 < ntiles) {
                #pragma unroll
                for (int ch = 0; ch < 4; ch++)
                    kpref[ch] = *(const float4*)&kbase[(size_t)(k0 + BK + lr) * HD + lc + ch * 32];
            }
            __syncthreads();  // V, Ps visible

            // ---- PV: O[rr][c] = O*alpha + sum_j P[j][i0+rr] * V[j][dd0+c]
            #pragma unroll
            for (int rr = 0; rr < 4; rr++)
                #pragma unroll
                for (int c = 0; c < 8; c++)
                    O[rr][c] *= alpha[rr];
            #pragma unroll 4
            for (int j = 0; j < BK; j++) {
                float4 pj = *(const float4*)&Ps[j * PSTR + i0];
                float4 v0 = *(const float4*)&KV[j * KVSTR + dd0];
                float4 v1 = *(const float4*)&KV[j * KVSTR + dd0 + 4];
                const float pr[4] = {pj.x, pj.y, pj.z, pj.w};
                const float vv[8] = {v0.x, v0.y, v0.z, v0.w, v1.x, v1.y, v1.z, v1.w};
                #pragma unroll
                for (int rr = 0; rr < 4; rr++)
                    #pragma unroll
                    for (int c = 0; c < 8; c++)
                        O[rr][c] += pr[rr] * vv[c];
            }
            __syncthreads();  // PV done -> KV/Ps free for next tile
        }

        // ---- epilogue: divide by l, store ctx [S, H, HD]
        #pragma unroll
        for (int rr = 0; rr < 4; rr++) {
            const float inv = 1.0f / l[rr];
            const int qg = q0 + i0 + rr;
            float4 o0 = make_float4(O[rr][0] * inv, O[rr][1] * inv,
                                    O[rr][2] * inv, O[rr][3] * inv);
            float4 o1 = make_float4(O[rr][4] * inv, O[rr][5] * inv,
                                    O[rr][6] * inv, O[rr][7] * inv);
            float* dst = &ctx[((size_t)qg * H + h) * HD + dd0];
            *(float4*)&dst[0] = o0;
            *(float4*)&dst[4] = o1;
        }
        __syncthreads();  // before next phase overwrites Qs
    }
}

// ---------------------------------------------------------------------------
// Dense output GEMM (unchanged): out = ctx @ Wdense + bdense
// ---------------------------------------------------------------------------
__global__ __launch_bounds__(256) void gemm_dense_kernel(
    const float* __restrict__ A, const float* __restrict__ W,
    const float* __restrict__ bias, float* __restrict__ out)
{
    __shared__ float As[16][68];
    __shared__ float Bs[16][64];
    const int bx = blockIdx.x;
    const int by = blockIdx.y;
    const int tid = threadIdx.x;
    const int tx = tid & 15, ty = tid >> 4;
    const int row0 = by * 64, col0 = bx * 64;

    const int am = tid >> 2;
    const int ak = (tid & 3) * 4;
    const int bk = tid >> 4;
    const int bn = (tid & 15) * 4;

    float acc[4][4] = {};

    for (int k0 = 0; k0 < D; k0 += 16) {
        float4 av = *(const float4*)&A[(size_t)(row0 + am) * D + k0 + ak];
        float4 bv = *(const float4*)&W[(size_t)(k0 + bk) * D + col0 + bn];
        __syncthreads();
        As[ak + 0][am] = av.x; As[ak + 1][am] = av.y;
        As[ak + 2][am] = av.z; As[ak + 3][am] = av.w;
        *(float4*)&Bs[bk][bn] = bv;
        __syncthreads();
        #pragma unroll
        for (int k = 0; k < 16; k++) {
            float4 a4 = *(const float4*)&As[k][ty * 4];
            float4 b4 = *(const float4*)&Bs[k][tx * 4];
            float a[4] = {a4.x, a4.y, a4.z, a4.w};
            float b[4] = {b4.x, b4.y, b4.z, b4.w};
            #pragma unroll
            for (int r = 0; r < 4; r++)
                #pragma unroll
                for (int c = 0; c < 4; c++)
                    acc[r][c] += a[r] * b[c];
        }
    }

    const int j0 = col0 + tx * 4;
    const float bv0 = bias[j0 + 0], bv1 = bias[j0 + 1];
    const float bv2 = bias[j0 + 2], bv3 = bias[j0 + 3];
    #pragma unroll
    for (int r = 0; r < 4; r++) {
        const int grow = row0 + ty * 4 + r;
        float4 o4 = make_float4(acc[r][0] + bv0, acc[r][1] + bv1,
                                acc[r][2] + bv2, acc[r][3] + bv3);
        *(float4*)&out[(size_t)grow * D + j0] = o4;
    }
}

extern "C" void kernel_launch(void* const* d_in, const int* in_sizes, int n_in,
                              void* d_out, int out_size, void* d_ws, size_t ws_size,
                              hipStream_t stream) {
    const float* x      = (const float*)d_in[0];
    const float* freqs  = (const float*)d_in[1];
    const int*   pos    = (const int*)d_in[2];
    const float* Wqkv   = (const float*)d_in[3];
    const float* bqkv   = (const float*)d_in[4];
    const float* Wdense = (const float*)d_in[5];
    const float* bdense = (const float*)d_in[6];
    float* out = (float*)d_out;

    float* qb  = (float*)d_ws;
    float* kb  = qb + (size_t)H * S * HD;
    float* vb  = kb + (size_t)H * S * HD;
    float* ctx = vb + (size_t)H * S * HD;

    dim3 g1(N3 / 64, S / 64);
    gemm_qkv_kernel<<<g1, 256, 0, stream>>>(x, Wqkv, bqkv, freqs, pos, qb, kb, vb);

    dim3 g2(16, H);  // 16 q-tile pairs x 16 heads = 256 blocks, uniform work
    attn_kernel<<<g2, 256, 0, stream>>>(qb, kb, vb, ctx);

    dim3 g3(D / 64, S / 64);
    gemm_dense_kernel<<<g3, 256, 0, stream>>>(ctx, Wdense, bdense, out);
}

// Round 3
// 1465.534 us; speedup vs baseline: 3.8702x; 1.0627x over previous
//
#include <hip/hip_runtime.h>

#define S 2048
#define D 2048
#define H 16
#define HD 128
#define N3 6144  // 3*D

typedef __attribute__((ext_vector_type(8))) short bf16x8;
typedef __attribute__((ext_vector_type(4))) float f32x4;
typedef unsigned short ushort_t;
typedef unsigned int uint_t;

// ---------------------------------------------------------------------------
// bf16 split helpers (round-to-nearest-even)
// ---------------------------------------------------------------------------
__device__ __forceinline__ ushort_t bf16_rne(float f) {
    uint_t u = __float_as_uint(f);
    u += 0x7fffu + ((u >> 16) & 1u);
    return (ushort_t)(u >> 16);
}
__device__ __forceinline__ float bf16_f32(ushort_t h) {
    return __uint_as_float(((uint_t)h) << 16);
}

// split f32 row-major -> hi/lo bf16 row-major (same layout)
__global__ __launch_bounds__(256) void convert_split_kernel(
    const float* __restrict__ in, ushort_t* __restrict__ hi,
    ushort_t* __restrict__ lo)
{
    const int i = blockIdx.x * 256 + threadIdx.x;  // per float4
    float4 v = ((const float4*)in)[i];
    ushort_t h0 = bf16_rne(v.x), h1 = bf16_rne(v.y);
    ushort_t h2 = bf16_rne(v.z), h3 = bf16_rne(v.w);
    ushort4 hv = make_ushort4(h0, h1, h2, h3);
    ushort4 lv = make_ushort4(bf16_rne(v.x - bf16_f32(h0)),
                              bf16_rne(v.y - bf16_f32(h1)),
                              bf16_rne(v.z - bf16_f32(h2)),
                              bf16_rne(v.w - bf16_f32(h3)));
    ((ushort4*)hi)[i] = hv;
    ((ushort4*)lo)[i] = lv;
}

// W [K][N] f32 -> Wt hi/lo [N][K] bf16 (transpose + split), 32x32 tiles
__global__ __launch_bounds__(256) void convert_split_t_kernel(
    const float* __restrict__ in, ushort_t* __restrict__ hi,
    ushort_t* __restrict__ lo, int Kdim, int Ndim)
{
    __shared__ float tile[32][33];
    const int k0 = blockIdx.x * 32, n0 = blockIdx.y * 32;
    const int tx = threadIdx.x & 31, ty = threadIdx.x >> 5;  // ty 0..7
    #pragma unroll
    for (int r = 0; r < 4; r++)
        tile[ty + r * 8][tx] = in[(size_t)(k0 + ty + r * 8) * Ndim + n0 + tx];
    __syncthreads();
    #pragma unroll
    for (int r = 0; r < 4; r++) {
        const int n = n0 + ty + r * 8;
        const int k = k0 + tx;
        float v = tile[tx][ty + r * 8];
        ushort_t h = bf16_rne(v);
        hi[(size_t)n * Kdim + k] = h;
        lo[(size_t)n * Kdim + k] = bf16_rne(v - bf16_f32(h));
    }
}

// ---------------------------------------------------------------------------
// Split-bf16 MFMA GEMM core: C(128x128) += (Ah+Al) @ (Bh+Bl)^T-ish, 3 terms.
// A row-major [M][K] bf16; B supplied transposed [N][K] bf16. 256 threads,
// 4 waves in 2x2, each wave 64x64 via 4x4 tiles of mfma_f32_16x16x32_bf16.
// LDS rows padded to 40 elems (80 B): frag-read bank starts 20m mod 32 ->
// 2-way aliasing only (free).
// ---------------------------------------------------------------------------
#define BK 32
#define LSTR 40
#define TILE_LDS (128 * LSTR)

__device__ __forceinline__ void mm_core_split(
    const ushort_t* __restrict__ Agh, const ushort_t* __restrict__ Agl,
    const ushort_t* __restrict__ Bgh, const ushort_t* __restrict__ Bgl,
    const int K, ushort_t* lds, const int t, f32x4 (&acc)[4][4])
{
    ushort_t* As_h = lds;
    ushort_t* As_l = lds + TILE_LDS;
    ushort_t* Bs_h = lds + 2 * TILE_LDS;
    ushort_t* Bs_l = lds + 3 * TILE_LDS;

    const int lrow = t >> 2;          // 0..63 staging row
    const int lkc  = (t & 3) * 8;     // staging k-chunk (elems)
    const int lane = t & 63;
    const int quad = lane >> 4;
    const int lr   = lane & 15;
    const int wm = ((t >> 6) & 1) * 64;
    const int wn = ((t >> 6) >> 1) * 64;

    uint4 pf[8];
#define DO_LOADS(k0)                                                          \
    {                                                                         \
        pf[0] = *(const uint4*)&Agh[(size_t)lrow * K + (k0) + lkc];           \
        pf[1] = *(const uint4*)&Agh[(size_t)(lrow + 64) * K + (k0) + lkc];    \
        pf[2] = *(const uint4*)&Agl[(size_t)lrow * K + (k0) + lkc];           \
        pf[3] = *(const uint4*)&Agl[(size_t)(lrow + 64) * K + (k0) + lkc];    \
        pf[4] = *(const uint4*)&Bgh[(size_t)lrow * K + (k0) + lkc];           \
        pf[5] = *(const uint4*)&Bgh[(size_t)(lrow + 64) * K + (k0) + lkc];    \
        pf[6] = *(const uint4*)&Bgl[(size_t)lrow * K + (k0) + lkc];           \
        pf[7] = *(const uint4*)&Bgl[(size_t)(lrow + 64) * K + (k0) + lkc];    \
    }
    DO_LOADS(0);

    for (int k0 = 0; k0 < K; k0 += BK) {
        __syncthreads();  // previous tile's compute done
        *(uint4*)&As_h[lrow * LSTR + lkc] = pf[0];
        *(uint4*)&As_h[(lrow + 64) * LSTR + lkc] = pf[1];
        *(uint4*)&As_l[lrow * LSTR + lkc] = pf[2];
        *(uint4*)&As_l[(lrow + 64) * LSTR + lkc] = pf[3];
        *(uint4*)&Bs_h[lrow * LSTR + lkc] = pf[4];
        *(uint4*)&Bs_h[(lrow + 64) * LSTR + lkc] = pf[5];
        *(uint4*)&Bs_l[lrow * LSTR + lkc] = pf[6];
        *(uint4*)&Bs_l[(lrow + 64) * LSTR + lkc] = pf[7];
        __syncthreads();
        if (k0 + BK < K) DO_LOADS(k0 + BK);

        bf16x8 af_h[4], af_l[4], bf_h[4], bf_l[4];
        #pragma unroll
        for (int i = 0; i < 4; i++) {
            af_h[i] = *(const bf16x8*)&As_h[(wm + i * 16 + lr) * LSTR + quad * 8];
            af_l[i] = *(const bf16x8*)&As_l[(wm + i * 16 + lr) * LSTR + quad * 8];
            bf_h[i] = *(const bf16x8*)&Bs_h[(wn + i * 16 + lr) * LSTR + quad * 8];
            bf_l[i] = *(const bf16x8*)&Bs_l[(wn + i * 16 + lr) * LSTR + quad * 8];
        }
        #pragma unroll
        for (int mt = 0; mt < 4; mt++)
            #pragma unroll
            for (int nt = 0; nt < 4; nt++) {
                acc[mt][nt] = __builtin_amdgcn_mfma_f32_16x16x32_bf16(
                    af_h[mt], bf_h[nt], acc[mt][nt], 0, 0, 0);
                acc[mt][nt] = __builtin_amdgcn_mfma_f32_16x16x32_bf16(
                    af_h[mt], bf_l[nt], acc[mt][nt], 0, 0, 0);
                acc[mt][nt] = __builtin_amdgcn_mfma_f32_16x16x32_bf16(
                    af_l[mt], bf_h[nt], acc[mt][nt], 0, 0, 0);
            }
    }
#undef DO_LOADS
}

// ---------------------------------------------------------------------------
// QKV GEMM (MFMA): qkv = x @ Wqkv + b, fused RoPE + scatter.
// Block covers 128 cols = exactly one head of one of q/k/v.
// ---------------------------------------------------------------------------
__global__ __launch_bounds__(256) void gemm_qkv_mfma(
    const ushort_t* __restrict__ xh, const ushort_t* __restrict__ xl,
    const ushort_t* __restrict__ Wth, const ushort_t* __restrict__ Wtl,
    const float* __restrict__ bias, const float* __restrict__ freqs,
    const int* __restrict__ input_pos,
    float* __restrict__ qb, float* __restrict__ kb, float* __restrict__ vb)
{
    __shared__ ushort_t lds[4 * TILE_LDS];
    const int t = threadIdx.x;
    const int col0 = blockIdx.x * 128;
    const int row0 = blockIdx.y * 128;

    f32x4 acc[4][4] = {};
    mm_core_split(xh + (size_t)row0 * D, xl + (size_t)row0 * D,
                  Wth + (size_t)col0 * D, Wtl + (size_t)col0 * D,
                  D, lds, t, acc);

    const int lane = t & 63;
    const int quad = lane >> 4;
    const int lr   = lane & 15;
    const int wm = ((t >> 6) & 1) * 64;
    const int wn = ((t >> 6) >> 1) * 64;

    const int which = col0 >> 11;           // 0=q 1=k 2=v
    const int hh = (col0 & 2047) >> 7;
    float* obase = (which == 0) ? qb : (which == 1) ? kb : vb;
    obase += (size_t)hh * S * HD;

    #pragma unroll
    for (int nt = 0; nt < 4; nt++) {
        const int d = wn + nt * 16 + lr;    // 0..127 within head
        const float bsc = bias[col0 + d];
        #pragma unroll
        for (int mt = 0; mt < 4; mt++) {
            #pragma unroll
            for (int reg = 0; reg < 4; reg++) {
                const int m = row0 + wm + mt * 16 + quad * 4 + reg;
                float v = acc[mt][nt][reg] + bsc;
                float o;
                if (which == 2) {
                    o = v;
                } else {
                    const float* fc = &freqs[((size_t)m * 64 + (d >> 1)) * 2];
                    const float c = fc[0], s = fc[1];
                    const float p = __shfl_xor(v, 1);
                    o = (d & 1) ? (v * c + p * s) : (v * c - p * s);
                }
                const float po = __shfl_xor(o, 1);
                if (!(d & 1)) {
                    const int srow = (which == 0) ? m : input_pos[m];
                    *(float2*)&obase[(size_t)srow * HD + d] = make_float2(o, po);
                }
            }
        }
    }
}

// ---------------------------------------------------------------------------
// Dense GEMM (MFMA): out = ctx @ Wdense + b
// ---------------------------------------------------------------------------
__global__ __launch_bounds__(256) void gemm_dense_mfma(
    const ushort_t* __restrict__ Ah, const ushort_t* __restrict__ Al,
    const ushort_t* __restrict__ Wth, const ushort_t* __restrict__ Wtl,
    const float* __restrict__ bias, float* __restrict__ out)
{
    __shared__ ushort_t lds[4 * TILE_LDS];
    const int t = threadIdx.x;
    const int col0 = blockIdx.x * 128;
    const int row0 = blockIdx.y * 128;

    f32x4 acc[4][4] = {};
    mm_core_split(Ah + (size_t)row0 * D, Al + (size_t)row0 * D,
                  Wth + (size_t)col0 * D, Wtl + (size_t)col0 * D,
                  D, lds, t, acc);

    const int lane = t & 63;
    const int quad = lane >> 4;
    const int lr   = lane & 15;
    const int wm = ((t >> 6) & 1) * 64;
    const int wn = ((t >> 6) >> 1) * 64;

    #pragma unroll
    for (int nt = 0; nt < 4; nt++) {
        const int n = col0 + wn + nt * 16 + lr;
        const float bsc = bias[n];
        #pragma unroll
        for (int mt = 0; mt < 4; mt++) {
            #pragma unroll
            for (int reg = 0; reg < 4; reg++) {
                const int m = row0 + wm + mt * 16 + quad * 4 + reg;
                const float o = acc[mt][nt][reg] + bsc;
                const float po = __shfl_xor(o, 1);
                if (!(n & 1))
                    *(float2*)&out[(size_t)m * D + n] = make_float2(o, po);
            }
        }
    }
}

// ---------------------------------------------------------------------------
// Flash attention (unchanged from R2).
// ---------------------------------------------------------------------------
#define BQ 64
#define ABK 32
#define QSTR 132
#define KVSTR 132
#define PSTR 68

__global__ __launch_bounds__(256) void attn_kernel(
    const float* __restrict__ qb, const float* __restrict__ kb,
    const float* __restrict__ vb, float* __restrict__ ctx)
{
    __shared__ float Qs[BQ * QSTR];
    __shared__ float KV[ABK * KVSTR];
    __shared__ float Ps[ABK * PSTR];

    const int pa = blockIdx.x;
    const int h  = blockIdx.y;
    const int t  = threadIdx.x;
    const int ty = t >> 4, tx = t & 15;
    const int i0  = ty * 4;
    const int j0  = tx * 2;
    const int dd0 = tx * 8;
    const int lr = t >> 3;
    const int lc = (t & 7) * 4;

    const float* kbase = kb + (size_t)h * S * HD;
    const float* vbase = vb + (size_t)h * S * HD;
    const float kSc = 0.08838834764831845f * 1.4426950408889634f;

    for (int ph = 0; ph < 2; ph++) {
        const int r = (ph == 0) ? pa : 31 - pa;
        const int q0 = r * BQ;
        const int ntiles = 2 * r + 2;

        #pragma unroll
        for (int pp = 0; pp < 2; pp++) {
            const int iq = lr + pp * 32;
            const float* src = qb + ((size_t)h * S + q0 + iq) * HD;
            #pragma unroll
            for (int ch = 0; ch < 4; ch++)
                *(float4*)&Qs[iq * QSTR + lc + ch * 32] =
                    *(const float4*)&src[lc + ch * 32];
        }

        float O[4][8] = {};
        float m[4], l[4];
        #pragma unroll
        for (int rr = 0; rr < 4; rr++) { m[rr] = -1e30f; l[rr] = 0.f; }

        float4 kpref[4];
        #pragma unroll
        for (int ch = 0; ch < 4; ch++)
            kpref[ch] = *(const float4*)&kbase[(size_t)lr * HD + lc + ch * 32];

        __syncthreads();

        for (int kt = 0; kt < ntiles; kt++) {
            const int k0 = kt * ABK;

            #pragma unroll
            for (int ch = 0; ch < 4; ch++)
                *(float4*)&KV[lr * KVSTR + lc + ch * 32] = kpref[ch];
            __syncthreads();

            float4 vpref[4];
            #pragma unroll
            for (int ch = 0; ch < 4; ch++)
                vpref[ch] = *(const float4*)&vbase[(size_t)(k0 + lr) * HD + lc + ch * 32];

            float acc[4][2] = {};
            #pragma unroll 4
            for (int d0 = 0; d0 < HD; d0 += 4) {
                float4 ka = *(const float4*)&KV[(j0 + 0) * KVSTR + d0];
                float4 kb4 = *(const float4*)&KV[(j0 + 1) * KVSTR + d0];
                #pragma unroll
                for (int rr = 0; rr < 4; rr++) {
                    float4 q4 = *(const float4*)&Qs[(i0 + rr) * QSTR + d0];
                    acc[rr][0] += q4.x * ka.x + q4.y * ka.y + q4.z * ka.z + q4.w * ka.w;
                    acc[rr][1] += q4.x * kb4.x + q4.y * kb4.y + q4.z * kb4.z + q4.w * kb4.w;
                }
            }

            const bool need_mask = (k0 + ABK - 1) > q0;
            float p[4][2], alpha[4];
            #pragma unroll
            for (int rr = 0; rr < 4; rr++) {
                float z0 = acc[rr][0] * kSc;
                float z1 = acc[rr][1] * kSc;
                if (need_mask) {
                    if (k0 + j0 + 0 > q0 + i0 + rr) z0 = -1e30f;
                    if (k0 + j0 + 1 > q0 + i0 + rr) z1 = -1e30f;
                }
                float rmax = fmaxf(z0, z1);
                #pragma unroll
                for (int off = 1; off < 16; off <<= 1)
                    rmax = fmaxf(rmax, __shfl_xor(rmax, off, 16));
                const float nm = fmaxf(m[rr], rmax);
                alpha[rr] = exp2f(m[rr] - nm);
                p[rr][0] = exp2f(z0 - nm);
                p[rr][1] = exp2f(z1 - nm);
                float ts = p[rr][0] + p[rr][1];
                #pragma unroll
                for (int off = 1; off < 16; off <<= 1)
                    ts += __shfl_xor(ts, off, 16);
                l[rr] = l[rr] * alpha[rr] + ts;
                m[rr] = nm;
            }
            __syncthreads();

            #pragma unroll
            for (int ch = 0; ch < 4; ch++)
                *(float4*)&KV[lr * KVSTR + lc + ch * 32] = vpref[ch];
            *(float4*)&Ps[(j0 + 0) * PSTR + i0] =
                make_float4(p[0][0], p[1][0], p[2][0], p[3][0]);
            *(float4*)&Ps[(j0 + 1) * PSTR + i0] =
                make_float4(p[0][1], p[1][1], p[2][1], p[3][1]);
            if (kt + 1 < ntiles) {
                #pragma unroll
                for (int ch = 0; ch < 4; ch++)
                    kpref[ch] = *(const float4*)&kbase[(size_t)(k0 + ABK + lr) * HD + lc + ch * 32];
            }
            __syncthreads();

            #pragma unroll
            for (int rr = 0; rr < 4; rr++)
                #pragma unroll
                for (int c = 0; c < 8; c++)
                    O[rr][c] *= alpha[rr];
            #pragma unroll 4
            for (int j = 0; j < ABK; j++) {
                float4 pj = *(const float4*)&Ps[j * PSTR + i0];
                float4 v0 = *(const float4*)&KV[j * KVSTR + dd0];
                float4 v1 = *(const float4*)&KV[j * KVSTR + dd0 + 4];
                const float pr[4] = {pj.x, pj.y, pj.z, pj.w};
                const float vv[8] = {v0.x, v0.y, v0.z, v0.w, v1.x, v1.y, v1.z, v1.w};
                #pragma unroll
                for (int rr = 0; rr < 4; rr++)
                    #pragma unroll
                    for (int c = 0; c < 8; c++)
                        O[rr][c] += pr[rr] * vv[c];
            }
            __syncthreads();
        }

        #pragma unroll
        for (int rr = 0; rr < 4; rr++) {
            const float inv = 1.0f / l[rr];
            const int qg = q0 + i0 + rr;
            float4 o0 = make_float4(O[rr][0] * inv, O[rr][1] * inv,
                                    O[rr][2] * inv, O[rr][3] * inv);
            float4 o1 = make_float4(O[rr][4] * inv, O[rr][5] * inv,
                                    O[rr][6] * inv, O[rr][7] * inv);
            float* dst = &ctx[((size_t)qg * H + h) * HD + dd0];
            *(float4*)&dst[0] = o0;
            *(float4*)&dst[4] = o1;
        }
        __syncthreads();
    }
}

// ---------------------------------------------------------------------------
// Fallback f32 GEMMs (R2, known-good) for small workspace.
// ---------------------------------------------------------------------------
__global__ __launch_bounds__(256) void gemm_qkv_kernel(
    const float* __restrict__ x, const float* __restrict__ W,
    const float* __restrict__ bias, const float* __restrict__ freqs,
    const int* __restrict__ input_pos,
    float* __restrict__ qb, float* __restrict__ kb, float* __restrict__ vb)
{
    __shared__ float As[16][68];
    __shared__ float Bs[16][64];
    const int bx = blockIdx.x;
    const int by = blockIdx.y;
    const int tid = threadIdx.x;
    const int tx = tid & 15, ty = tid >> 4;
    const int row0 = by * 64, col0 = bx * 64;
    const int am = tid >> 2;
    const int ak = (tid & 3) * 4;
    const int bk = tid >> 4;
    const int bn = (tid & 15) * 4;
    float acc[4][4] = {};
    for (int k0 = 0; k0 < D; k0 += 16) {
        float4 av = *(const float4*)&x[(size_t)(row0 + am) * D + k0 + ak];
        float4 bv = *(const float4*)&W[(size_t)(k0 + bk) * N3 + col0 + bn];
        __syncthreads();
        As[ak + 0][am] = av.x; As[ak + 1][am] = av.y;
        As[ak + 2][am] = av.z; As[ak + 3][am] = av.w;
        *(float4*)&Bs[bk][bn] = bv;
        __syncthreads();
        #pragma unroll
        for (int k = 0; k < 16; k++) {
            float4 a4 = *(const float4*)&As[k][ty * 4];
            float4 b4 = *(const float4*)&Bs[k][tx * 4];
            float a[4] = {a4.x, a4.y, a4.z, a4.w};
            float b[4] = {b4.x, b4.y, b4.z, b4.w};
            #pragma unroll
            for (int r = 0; r < 4; r++)
                #pragma unroll
                for (int c = 0; c < 4; c++)
                    acc[r][c] += a[r] * b[c];
        }
    }
    const int j0 = col0 + tx * 4;
    const int which = j0 >> 11;
    const int hh = (j0 & 2047) >> 7;
    const int d0 = j0 & 127;
    const float bv0 = bias[j0 + 0], bv1 = bias[j0 + 1];
    const float bv2 = bias[j0 + 2], bv3 = bias[j0 + 3];
    #pragma unroll
    for (int r = 0; r < 4; r++) {
        const int grow = row0 + ty * 4 + r;
        float v0 = acc[r][0] + bv0, v1 = acc[r][1] + bv1;
        float v2 = acc[r][2] + bv2, v3 = acc[r][3] + bv3;
        if (which == 2) {
            const int pos = input_pos[grow];
            float4 o4 = make_float4(v0, v1, v2, v3);
            *(float4*)&vb[((size_t)hh * S + pos) * HD + d0] = o4;
        } else {
            const float* fc = &freqs[((size_t)grow * 64 + (d0 >> 1)) * 2];
            float c0 = fc[0], s0 = fc[1], c1 = fc[2], s1 = fc[3];
            float o0 = v0 * c0 - v1 * s0, o1 = v1 * c0 + v0 * s0;
            float o2 = v2 * c1 - v3 * s1, o3 = v3 * c1 + v2 * s1;
            float4 o4 = make_float4(o0, o1, o2, o3);
            if (which == 0) {
                *(float4*)&qb[((size_t)hh * S + grow) * HD + d0] = o4;
            } else {
                const int pos = input_pos[grow];
                *(float4*)&kb[((size_t)hh * S + pos) * HD + d0] = o4;
            }
        }
    }
}

__global__ __launch_bounds__(256) void gemm_dense_kernel(
    const float* __restrict__ A, const float* __restrict__ W,
    const float* __restrict__ bias, float* __restrict__ out)
{
    __shared__ float As[16][68];
    __shared__ float Bs[16][64];
    const int bx = blockIdx.x;
    const int by = blockIdx.y;
    const int tid = threadIdx.x;
    const int tx = tid & 15, ty = tid >> 4;
    const int row0 = by * 64, col0 = bx * 64;
    const int am = tid >> 2;
    const int ak = (tid & 3) * 4;
    const int bk = tid >> 4;
    const int bn = (tid & 15) * 4;
    float acc[4][4] = {};
    for (int k0 = 0; k0 < D; k0 += 16) {
        float4 av = *(const float4*)&A[(size_t)(row0 + am) * D + k0 + ak];
        float4 bv = *(const float4*)&W[(size_t)(k0 + bk) * D + col0 + bn];
        __syncthreads();
        As[ak + 0][am] = av.x; As[ak + 1][am] = av.y;
        As[ak + 2][am] = av.z; As[ak + 3][am] = av.w;
        *(float4*)&Bs[bk][bn] = bv;
        __syncthreads();
        #pragma unroll
        for (int k = 0; k < 16; k++) {
            float4 a4 = *(const float4*)&As[k][ty * 4];
            float4 b4 = *(const float4*)&Bs[k][tx * 4];
            float a[4] = {a4.x, a4.y, a4.z, a4.w};
            float b[4] = {b4.x, b4.y, b4.z, b4.w};
            #pragma unroll
            for (int r = 0; r < 4; r++)
                #pragma unroll
                for (int c = 0; c < 4; c++)
                    acc[r][c] += a[r] * b[c];
        }
    }
    const int j0 = col0 + tx * 4;
    const float bv0 = bias[j0 + 0], bv1 = bias[j0 + 1];
    const float bv2 = bias[j0 + 2], bv3 = bias[j0 + 3];
    #pragma unroll
    for (int r = 0; r < 4; r++) {
        const int grow = row0 + ty * 4 + r;
        float4 o4 = make_float4(acc[r][0] + bv0, acc[r][1] + bv1,
                                acc[r][2] + bv2, acc[r][3] + bv3);
        *(float4*)&out[(size_t)grow * D + j0] = o4;
    }
}

extern "C" void kernel_launch(void* const* d_in, const int* in_sizes, int n_in,
                              void* d_out, int out_size, void* d_ws, size_t ws_size,
                              hipStream_t stream) {
    const float* x      = (const float*)d_in[0];
    const float* freqs  = (const float*)d_in[1];
    const int*   pos    = (const int*)d_in[2];
    const float* Wqkv   = (const float*)d_in[3];
    const float* bqkv   = (const float*)d_in[4];
    const float* Wdense = (const float*)d_in[5];
    const float* bdense = (const float*)d_in[6];
    float* out = (float*)d_out;

    // f32 region: qb, kb, vb [H,S,HD], ctx [S,D]  (64 MiB)
    float* qb  = (float*)d_ws;
    float* kb  = qb + (size_t)H * S * HD;
    float* vb  = kb + (size_t)H * S * HD;
    float* ctx = vb + (size_t)H * S * HD;

    const size_t nSD = (size_t)S * D;           // 4 Mi elems
    const size_t needed =
        4 * nSD * 4 +                            // qb,kb,vb,ctx f32
        4 * nSD * 2 +                            // xh,xl,ctxh,ctxl bf16
        2 * (size_t)D * N3 * 2 +                 // Wqkv_t hi/lo bf16
        2 * nSD * 2;                             // Wdense_t hi/lo bf16

    if (ws_size >= needed) {
        ushort_t* xh   = (ushort_t*)(ctx + nSD);
        ushort_t* xl   = xh + nSD;
        ushort_t* ctxh = xl + nSD;
        ushort_t* ctxl = ctxh + nSD;
        ushort_t* Wth  = ctxl + nSD;
        ushort_t* Wtl  = Wth + (size_t)D * N3;
        ushort_t* Wdth = Wtl + (size_t)D * N3;
        ushort_t* Wdtl = Wdth + nSD;

        convert_split_kernel<<<nSD / 4 / 256, 256, 0, stream>>>(x, xh, xl);
        dim3 gt1(D / 32, N3 / 32);
        convert_split_t_kernel<<<gt1, 256, 0, stream>>>(Wqkv, Wth, Wtl, D, N3);
        dim3 gt2(D / 32, D / 32);
        convert_split_t_kernel<<<gt2, 256, 0, stream>>>(Wdense, Wdth, Wdtl, D, D);

        dim3 g1(N3 / 128, S / 128);
        gemm_qkv_mfma<<<g1, 256, 0, stream>>>(xh, xl, Wth, Wtl, bqkv, freqs,
                                              pos, qb, kb, vb);
        dim3 g2(16, H);
        attn_kernel<<<g2, 256, 0, stream>>>(qb, kb, vb, ctx);

        convert_split_kernel<<<nSD / 4 / 256, 256, 0, stream>>>(ctx, ctxh, ctxl);
        dim3 g3(D / 128, S / 128);
        gemm_dense_mfma<<<g3, 256, 0, stream>>>(ctxh, ctxl, Wdth, Wdtl, bdense, out);
    } else {
        // fallback: R2 f32 path (needs only 64 MiB)
        dim3 g1(N3 / 64, S / 64);
        gemm_qkv_kernel<<<g1, 256, 0, stream>>>(x, Wqkv, bqkv, freqs, pos, qb, kb, vb);
        dim3 g2(16, H);
        attn_kernel<<<g2, 256, 0, stream>>>(qb, kb, vb, ctx);
        dim3 g3(D / 64, S / 64);
        gemm_dense_kernel<<<g3, 256, 0, stream>>>(ctx, Wdense, bdense, out);
    }
}

// Round 4
// 990.869 us; speedup vs baseline: 5.7242x; 1.4790x over previous
//
#include <hip/hip_runtime.h>

#define S 2048
#define D 2048
#define H 16
#define HD 128
#define N3 6144  // 3*D

typedef __attribute__((ext_vector_type(8))) short bf16x8;
typedef __attribute__((ext_vector_type(4))) float f32x4;
typedef unsigned short ushort_t;
typedef unsigned int uint_t;

// ---------------------------------------------------------------------------
// bf16 split helpers (round-to-nearest-even)
// ---------------------------------------------------------------------------
__device__ __forceinline__ ushort_t bf16_rne(float f) {
    uint_t u = __float_as_uint(f);
    u += 0x7fffu + ((u >> 16) & 1u);
    return (ushort_t)(u >> 16);
}
__device__ __forceinline__ float bf16_f32(ushort_t h) {
    return __uint_as_float(((uint_t)h) << 16);
}

// split f32 row-major -> hi/lo bf16 row-major (same layout)
__global__ __launch_bounds__(256) void convert_split_kernel(
    const float* __restrict__ in, ushort_t* __restrict__ hi,
    ushort_t* __restrict__ lo)
{
    const int i = blockIdx.x * 256 + threadIdx.x;  // per float4
    float4 v = ((const float4*)in)[i];
    ushort_t h0 = bf16_rne(v.x), h1 = bf16_rne(v.y);
    ushort_t h2 = bf16_rne(v.z), h3 = bf16_rne(v.w);
    ushort4 hv = make_ushort4(h0, h1, h2, h3);
    ushort4 lv = make_ushort4(bf16_rne(v.x - bf16_f32(h0)),
                              bf16_rne(v.y - bf16_f32(h1)),
                              bf16_rne(v.z - bf16_f32(h2)),
                              bf16_rne(v.w - bf16_f32(h3)));
    ((ushort4*)hi)[i] = hv;
    ((ushort4*)lo)[i] = lv;
}

// W [K][N] f32 -> Wt hi/lo [N][K] bf16 (transpose + split), 32x32 tiles
__global__ __launch_bounds__(256) void convert_split_t_kernel(
    const float* __restrict__ in, ushort_t* __restrict__ hi,
    ushort_t* __restrict__ lo, int Kdim, int Ndim)
{
    __shared__ float tile[32][33];
    const int k0 = blockIdx.x * 32, n0 = blockIdx.y * 32;
    const int tx = threadIdx.x & 31, ty = threadIdx.x >> 5;  // ty 0..7
    #pragma unroll
    for (int r = 0; r < 4; r++)
        tile[ty + r * 8][tx] = in[(size_t)(k0 + ty + r * 8) * Ndim + n0 + tx];
    __syncthreads();
    #pragma unroll
    for (int r = 0; r < 4; r++) {
        const int n = n0 + ty + r * 8;
        const int k = k0 + tx;
        float v = tile[tx][ty + r * 8];
        ushort_t h = bf16_rne(v);
        hi[(size_t)n * Kdim + k] = h;
        lo[(size_t)n * Kdim + k] = bf16_rne(v - bf16_f32(h));
    }
}

// ---------------------------------------------------------------------------
// async global->LDS, 16 B per lane, wave-uniform LDS base (HW adds lane*16).
// ---------------------------------------------------------------------------
__device__ __forceinline__ void gload16(const ushort_t* g, ushort_t* l) {
    __builtin_amdgcn_global_load_lds(
        (const __attribute__((address_space(1))) unsigned int*)g,
        (__attribute__((address_space(3))) unsigned int*)l, 16, 0, 0);
}

// ---------------------------------------------------------------------------
// Split-bf16 MFMA GEMM core, m97-style: 128x128 tile, BK=32, 256 threads,
// 4 waves 2x2, each wave 64x64 via 4x4 mfma_f32_16x16x32_bf16, 3 terms
// (Ah*Bh + Ah*Bl + Al*Bh). Staging via global_load_lds (no VGPR prefetch,
// no spills). LDS streams UNPADDED [128][32] bf16 (wave-uniform-base
// constraint); 64 B rows are the m97 bank-benign layout for ds_read_b128.
// ---------------------------------------------------------------------------
#define BK 32
#define TILE_ELEMS (128 * BK)   // 4096 elems = 8 KB per stream

__device__ __forceinline__ void mm_core_split(
    const ushort_t* __restrict__ Agh, const ushort_t* __restrict__ Agl,
    const ushort_t* __restrict__ Bgh, const ushort_t* __restrict__ Bgl,
    const int K, ushort_t* lds, const int t, f32x4 (&acc)[4][4])
{
    ushort_t* As_h = lds;
    ushort_t* As_l = lds + TILE_ELEMS;
    ushort_t* Bs_h = lds + 2 * TILE_ELEMS;
    ushort_t* Bs_l = lds + 3 * TILE_ELEMS;

    const int lane = t & 63;
    const int wv   = t >> 6;          // wave id 0..3 (uniform in wave)
    const int lrow = lane >> 2;       // 0..15: row within 16-row group
    const int lk   = (lane & 3) * 8;  // 16B chunk: elem offset in row
    const int quad = lane >> 4;
    const int lr   = lane & 15;
    const int wm   = (wv & 1) * 64;
    const int wn   = (wv >> 1) * 64;

    const int r0  = wv * 16;          // this wave's row group (pass 0)
    const int lo0 = r0 * BK;          // LDS elem offset, pass 0 (uniform)
    const int lo1 = (r0 + 64) * BK;   // pass 1

    for (int k0 = 0; k0 < K; k0 += BK) {
        __syncthreads();  // previous tile's compute done reading LDS
        const size_t go0 = (size_t)(r0 + lrow) * K + k0 + lk;
        const size_t go1 = (size_t)(r0 + 64 + lrow) * K + k0 + lk;
        gload16(Agh + go0, As_h + lo0);
        gload16(Agh + go1, As_h + lo1);
        gload16(Agl + go0, As_l + lo0);
        gload16(Agl + go1, As_l + lo1);
        gload16(Bgh + go0, Bs_h + lo0);
        gload16(Bgh + go1, Bs_h + lo1);
        gload16(Bgl + go0, Bs_l + lo0);
        gload16(Bgl + go1, Bs_l + lo1);
        __syncthreads();  // compiler drains vmcnt(0) before barrier

        bf16x8 af_h[4], af_l[4], bf_h[4], bf_l[4];
        #pragma unroll
        for (int i = 0; i < 4; i++) {
            af_h[i] = *(const bf16x8*)&As_h[(wm + i * 16 + lr) * BK + quad * 8];
            af_l[i] = *(const bf16x8*)&As_l[(wm + i * 16 + lr) * BK + quad * 8];
            bf_h[i] = *(const bf16x8*)&Bs_h[(wn + i * 16 + lr) * BK + quad * 8];
            bf_l[i] = *(const bf16x8*)&Bs_l[(wn + i * 16 + lr) * BK + quad * 8];
        }
        #pragma unroll
        for (int mt = 0; mt < 4; mt++)
            #pragma unroll
            for (int nt = 0; nt < 4; nt++) {
                acc[mt][nt] = __builtin_amdgcn_mfma_f32_16x16x32_bf16(
                    af_h[mt], bf_h[nt], acc[mt][nt], 0, 0, 0);
                acc[mt][nt] = __builtin_amdgcn_mfma_f32_16x16x32_bf16(
                    af_h[mt], bf_l[nt], acc[mt][nt], 0, 0, 0);
                acc[mt][nt] = __builtin_amdgcn_mfma_f32_16x16x32_bf16(
                    af_l[mt], bf_h[nt], acc[mt][nt], 0, 0, 0);
            }
    }
}

// ---------------------------------------------------------------------------
// QKV GEMM (MFMA): qkv = x @ Wqkv + b, fused RoPE + scatter.
// Block covers 128 cols = exactly one head of one of q/k/v.
// ---------------------------------------------------------------------------
__global__ __launch_bounds__(256) void gemm_qkv_mfma(
    const ushort_t* __restrict__ xh, const ushort_t* __restrict__ xl,
    const ushort_t* __restrict__ Wth, const ushort_t* __restrict__ Wtl,
    const float* __restrict__ bias, const float* __restrict__ freqs,
    const int* __restrict__ input_pos,
    float* __restrict__ qb, float* __restrict__ kb, float* __restrict__ vb)
{
    __shared__ ushort_t lds[4 * TILE_ELEMS];
    const int t = threadIdx.x;
    const int col0 = blockIdx.x * 128;
    const int row0 = blockIdx.y * 128;

    f32x4 acc[4][4] = {};
    mm_core_split(xh + (size_t)row0 * D, xl + (size_t)row0 * D,
                  Wth + (size_t)col0 * D, Wtl + (size_t)col0 * D,
                  D, lds, t, acc);

    const int lane = t & 63;
    const int quad = lane >> 4;
    const int lr   = lane & 15;
    const int wm = ((t >> 6) & 1) * 64;
    const int wn = ((t >> 6) >> 1) * 64;

    const int which = col0 >> 11;           // 0=q 1=k 2=v
    const int hh = (col0 & 2047) >> 7;
    float* obase = (which == 0) ? qb : (which == 1) ? kb : vb;
    obase += (size_t)hh * S * HD;

    #pragma unroll
    for (int nt = 0; nt < 4; nt++) {
        const int d = wn + nt * 16 + lr;    // 0..127 within head
        const float bsc = bias[col0 + d];
        #pragma unroll
        for (int mt = 0; mt < 4; mt++) {
            #pragma unroll
            for (int reg = 0; reg < 4; reg++) {
                const int m = row0 + wm + mt * 16 + quad * 4 + reg;
                float v = acc[mt][nt][reg] + bsc;
                float o;
                if (which == 2) {
                    o = v;
                } else {
                    const float* fc = &freqs[((size_t)m * 64 + (d >> 1)) * 2];
                    const float c = fc[0], s = fc[1];
                    const float p = __shfl_xor(v, 1);
                    o = (d & 1) ? (v * c + p * s) : (v * c - p * s);
                }
                const float po = __shfl_xor(o, 1);
                if (!(d & 1)) {
                    const int srow = (which == 0) ? m : input_pos[m];
                    *(float2*)&obase[(size_t)srow * HD + d] = make_float2(o, po);
                }
            }
        }
    }
}

// ---------------------------------------------------------------------------
// Dense GEMM (MFMA): out = ctx @ Wdense + b
// ---------------------------------------------------------------------------
__global__ __launch_bounds__(256) void gemm_dense_mfma(
    const ushort_t* __restrict__ Ah, const ushort_t* __restrict__ Al,
    const ushort_t* __restrict__ Wth, const ushort_t* __restrict__ Wtl,
    const float* __restrict__ bias, float* __restrict__ out)
{
    __shared__ ushort_t lds[4 * TILE_ELEMS];
    const int t = threadIdx.x;
    const int col0 = blockIdx.x * 128;
    const int row0 = blockIdx.y * 128;

    f32x4 acc[4][4] = {};
    mm_core_split(Ah + (size_t)row0 * D, Al + (size_t)row0 * D,
                  Wth + (size_t)col0 * D, Wtl + (size_t)col0 * D,
                  D, lds, t, acc);

    const int lane = t & 63;
    const int quad = lane >> 4;
    const int lr   = lane & 15;
    const int wm = ((t >> 6) & 1) * 64;
    const int wn = ((t >> 6) >> 1) * 64;

    #pragma unroll
    for (int nt = 0; nt < 4; nt++) {
        const int n = col0 + wn + nt * 16 + lr;
        const float bsc = bias[n];
        #pragma unroll
        for (int mt = 0; mt < 4; mt++) {
            #pragma unroll
            for (int reg = 0; reg < 4; reg++) {
                const int m = row0 + wm + mt * 16 + quad * 4 + reg;
                const float o = acc[mt][nt][reg] + bsc;
                const float po = __shfl_xor(o, 1);
                if (!(n & 1))
                    *(float2*)&out[(size_t)m * D + n] = make_float2(o, po);
            }
        }
    }
}

// ---------------------------------------------------------------------------
// Flash attention (unchanged from R2/R3).
// ---------------------------------------------------------------------------
#define BQ 64
#define ABK 32
#define QSTR 132
#define KVSTR 132
#define PSTR 68

__global__ __launch_bounds__(256) void attn_kernel(
    const float* __restrict__ qb, const float* __restrict__ kb,
    const float* __restrict__ vb, float* __restrict__ ctx)
{
    __shared__ float Qs[BQ * QSTR];
    __shared__ float KV[ABK * KVSTR];
    __shared__ float Ps[ABK * PSTR];

    const int pa = blockIdx.x;
    const int h  = blockIdx.y;
    const int t  = threadIdx.x;
    const int ty = t >> 4, tx = t & 15;
    const int i0  = ty * 4;
    const int j0  = tx * 2;
    const int dd0 = tx * 8;
    const int lr = t >> 3;
    const int lc = (t & 7) * 4;

    const float* kbase = kb + (size_t)h * S * HD;
    const float* vbase = vb + (size_t)h * S * HD;
    const float kSc = 0.08838834764831845f * 1.4426950408889634f;

    for (int ph = 0; ph < 2; ph++) {
        const int r = (ph == 0) ? pa : 31 - pa;
        const int q0 = r * BQ;
        const int ntiles = 2 * r + 2;

        #pragma unroll
        for (int pp = 0; pp < 2; pp++) {
            const int iq = lr + pp * 32;
            const float* src = qb + ((size_t)h * S + q0 + iq) * HD;
            #pragma unroll
            for (int ch = 0; ch < 4; ch++)
                *(float4*)&Qs[iq * QSTR + lc + ch * 32] =
                    *(const float4*)&src[lc + ch * 32];
        }

        float O[4][8] = {};
        float m[4], l[4];
        #pragma unroll
        for (int rr = 0; rr < 4; rr++) { m[rr] = -1e30f; l[rr] = 0.f; }

        float4 kpref[4];
        #pragma unroll
        for (int ch = 0; ch < 4; ch++)
            kpref[ch] = *(const float4*)&kbase[(size_t)lr * HD + lc + ch * 32];

        __syncthreads();

        for (int kt = 0; kt < ntiles; kt++) {
            const int k0 = kt * ABK;

            #pragma unroll
            for (int ch = 0; ch < 4; ch++)
                *(float4*)&KV[lr * KVSTR + lc + ch * 32] = kpref[ch];
            __syncthreads();

            float4 vpref[4];
            #pragma unroll
            for (int ch = 0; ch < 4; ch++)
                vpref[ch] = *(const float4*)&vbase[(size_t)(k0 + lr) * HD + lc + ch * 32];

            float acc[4][2] = {};
            #pragma unroll 4
            for (int d0 = 0; d0 < HD; d0 += 4) {
                float4 ka = *(const float4*)&KV[(j0 + 0) * KVSTR + d0];
                float4 kb4 = *(const float4*)&KV[(j0 + 1) * KVSTR + d0];
                #pragma unroll
                for (int rr = 0; rr < 4; rr++) {
                    float4 q4 = *(const float4*)&Qs[(i0 + rr) * QSTR + d0];
                    acc[rr][0] += q4.x * ka.x + q4.y * ka.y + q4.z * ka.z + q4.w * ka.w;
                    acc[rr][1] += q4.x * kb4.x + q4.y * kb4.y + q4.z * kb4.z + q4.w * kb4.w;
                }
            }

            const bool need_mask = (k0 + ABK - 1) > q0;
            float p[4][2], alpha[4];
            #pragma unroll
            for (int rr = 0; rr < 4; rr++) {
                float z0 = acc[rr][0] * kSc;
                float z1 = acc[rr][1] * kSc;
                if (need_mask) {
                    if (k0 + j0 + 0 > q0 + i0 + rr) z0 = -1e30f;
                    if (k0 + j0 + 1 > q0 + i0 + rr) z1 = -1e30f;
                }
                float rmax = fmaxf(z0, z1);
                #pragma unroll
                for (int off = 1; off < 16; off <<= 1)
                    rmax = fmaxf(rmax, __shfl_xor(rmax, off, 16));
                const float nm = fmaxf(m[rr], rmax);
                alpha[rr] = exp2f(m[rr] - nm);
                p[rr][0] = exp2f(z0 - nm);
                p[rr][1] = exp2f(z1 - nm);
                float ts = p[rr][0] + p[rr][1];
                #pragma unroll
                for (int off = 1; off < 16; off <<= 1)
                    ts += __shfl_xor(ts, off, 16);
                l[rr] = l[rr] * alpha[rr] + ts;
                m[rr] = nm;
            }
            __syncthreads();

            #pragma unroll
            for (int ch = 0; ch < 4; ch++)
                *(float4*)&KV[lr * KVSTR + lc + ch * 32] = vpref[ch];
            *(float4*)&Ps[(j0 + 0) * PSTR + i0] =
                make_float4(p[0][0], p[1][0], p[2][0], p[3][0]);
            *(float4*)&Ps[(j0 + 1) * PSTR + i0] =
                make_float4(p[0][1], p[1][1], p[2][1], p[3][1]);
            if (kt + 1 < ntiles) {
                #pragma unroll
                for (int ch = 0; ch < 4; ch++)
                    kpref[ch] = *(const float4*)&kbase[(size_t)(k0 + ABK + lr) * HD + lc + ch * 32];
            }
            __syncthreads();

            #pragma unroll
            for (int rr = 0; rr < 4; rr++)
                #pragma unroll
                for (int c = 0; c < 8; c++)
                    O[rr][c] *= alpha[rr];
            #pragma unroll 4
            for (int j = 0; j < ABK; j++) {
                float4 pj = *(const float4*)&Ps[j * PSTR + i0];
                float4 v0 = *(const float4*)&KV[j * KVSTR + dd0];
                float4 v1 = *(const float4*)&KV[j * KVSTR + dd0 + 4];
                const float pr[4] = {pj.x, pj.y, pj.z, pj.w};
                const float vv[8] = {v0.x, v0.y, v0.z, v0.w, v1.x, v1.y, v1.z, v1.w};
                #pragma unroll
                for (int rr = 0; rr < 4; rr++)
                    #pragma unroll
                    for (int c = 0; c < 8; c++)
                        O[rr][c] += pr[rr] * vv[c];
            }
            __syncthreads();
        }

        #pragma unroll
        for (int rr = 0; rr < 4; rr++) {
            const float inv = 1.0f / l[rr];
            const int qg = q0 + i0 + rr;
            float4 o0 = make_float4(O[rr][0] * inv, O[rr][1] * inv,
                                    O[rr][2] * inv, O[rr][3] * inv);
            float4 o1 = make_float4(O[rr][4] * inv, O[rr][5] * inv,
                                    O[rr][6] * inv, O[rr][7] * inv);
            float* dst = &ctx[((size_t)qg * H + h) * HD + dd0];
            *(float4*)&dst[0] = o0;
            *(float4*)&dst[4] = o1;
        }
        __syncthreads();
    }
}

// ---------------------------------------------------------------------------
// Fallback f32 GEMMs (R2, known-good) for small workspace.
// ---------------------------------------------------------------------------
__global__ __launch_bounds__(256) void gemm_qkv_kernel(
    const float* __restrict__ x, const float* __restrict__ W,
    const float* __restrict__ bias, const float* __restrict__ freqs,
    const int* __restrict__ input_pos,
    float* __restrict__ qb, float* __restrict__ kb, float* __restrict__ vb)
{
    __shared__ float As[16][68];
    __shared__ float Bs[16][64];
    const int bx = blockIdx.x;
    const int by = blockIdx.y;
    const int tid = threadIdx.x;
    const int tx = tid & 15, ty = tid >> 4;
    const int row0 = by * 64, col0 = bx * 64;
    const int am = tid >> 2;
    const int ak = (tid & 3) * 4;
    const int bk = tid >> 4;
    const int bn = (tid & 15) * 4;
    float acc[4][4] = {};
    for (int k0 = 0; k0 < D; k0 += 16) {
        float4 av = *(const float4*)&x[(size_t)(row0 + am) * D + k0 + ak];
        float4 bv = *(const float4*)&W[(size_t)(k0 + bk) * N3 + col0 + bn];
        __syncthreads();
        As[ak + 0][am] = av.x; As[ak + 1][am] = av.y;
        As[ak + 2][am] = av.z; As[ak + 3][am] = av.w;
        *(float4*)&Bs[bk][bn] = bv;
        __syncthreads();
        #pragma unroll
        for (int k = 0; k < 16; k++) {
            float4 a4 = *(const float4*)&As[k][ty * 4];
            float4 b4 = *(const float4*)&Bs[k][tx * 4];
            float a[4] = {a4.x, a4.y, a4.z, a4.w};
            float b[4] = {b4.x, b4.y, b4.z, b4.w};
            #pragma unroll
            for (int r = 0; r < 4; r++)
                #pragma unroll
                for (int c = 0; c < 4; c++)
                    acc[r][c] += a[r] * b[c];
        }
    }
    const int j0 = col0 + tx * 4;
    const int which = j0 >> 11;
    const int hh = (j0 & 2047) >> 7;
    const int d0 = j0 & 127;
    const float bv0 = bias[j0 + 0], bv1 = bias[j0 + 1];
    const float bv2 = bias[j0 + 2], bv3 = bias[j0 + 3];
    #pragma unroll
    for (int r = 0; r < 4; r++) {
        const int grow = row0 + ty * 4 + r;
        float v0 = acc[r][0] + bv0, v1 = acc[r][1] + bv1;
        float v2 = acc[r][2] + bv2, v3 = acc[r][3] + bv3;
        if (which == 2) {
            const int pos = input_pos[grow];
            float4 o4 = make_float4(v0, v1, v2, v3);
            *(float4*)&vb[((size_t)hh * S + pos) * HD + d0] = o4;
        } else {
            const float* fc = &freqs[((size_t)grow * 64 + (d0 >> 1)) * 2];
            float c0 = fc[0], s0 = fc[1], c1 = fc[2], s1 = fc[3];
            float o0 = v0 * c0 - v1 * s0, o1 = v1 * c0 + v0 * s0;
            float o2 = v2 * c1 - v3 * s1, o3 = v3 * c1 + v2 * s1;
            float4 o4 = make_float4(o0, o1, o2, o3);
            if (which == 0) {
                *(float4*)&qb[((size_t)hh * S + grow) * HD + d0] = o4;
            } else {
                const int pos = input_pos[grow];
                *(float4*)&kb[((size_t)hh * S + pos) * HD + d0] = o4;
            }
        }
    }
}

__global__ __launch_bounds__(256) void gemm_dense_kernel(
    const float* __restrict__ A, const float* __restrict__ W,
    const float* __restrict__ bias, float* __restrict__ out)
{
    __shared__ float As[16][68];
    __shared__ float Bs[16][64];
    const int bx = blockIdx.x;
    const int by = blockIdx.y;
    const int tid = threadIdx.x;
    const int tx = tid & 15, ty = tid >> 4;
    const int row0 = by * 64, col0 = bx * 64;
    const int am = tid >> 2;
    const int ak = (tid & 3) * 4;
    const int bk = tid >> 4;
    const int bn = (tid & 15) * 4;
    float acc[4][4] = {};
    for (int k0 = 0; k0 < D; k0 += 16) {
        float4 av = *(const float4*)&A[(size_t)(row0 + am) * D + k0 + ak];
        float4 bv = *(const float4*)&W[(size_t)(k0 + bk) * D + col0 + bn];
        __syncthreads();
        As[ak + 0][am] = av.x; As[ak + 1][am] = av.y;
        As[ak + 2][am] = av.z; As[ak + 3][am] = av.w;
        *(float4*)&Bs[bk][bn] = bv;
        __syncthreads();
        #pragma unroll
        for (int k = 0; k < 16; k++) {
            float4 a4 = *(const float4*)&As[k][ty * 4];
            float4 b4 = *(const float4*)&Bs[k][tx * 4];
            float a[4] = {a4.x, a4.y, a4.z, a4.w};
            float b[4] = {b4.x, b4.y, b4.z, b4.w};
            #pragma unroll
            for (int r = 0; r < 4; r++)
                #pragma unroll
                for (int c = 0; c < 4; c++)
                    acc[r][c] += a[r] * b[c];
        }
    }
    const int j0 = col0 + tx * 4;
    const float bv0 = bias[j0 + 0], bv1 = bias[j0 + 1];
    const float bv2 = bias[j0 + 2], bv3 = bias[j0 + 3];
    #pragma unroll
    for (int r = 0; r < 4; r++) {
        const int grow = row0 + ty * 4 + r;
        float4 o4 = make_float4(acc[r][0] + bv0, acc[r][1] + bv1,
                                acc[r][2] + bv2, acc[r][3] + bv3);
        *(float4*)&out[(size_t)grow * D + j0] = o4;
    }
}

extern "C" void kernel_launch(void* const* d_in, const int* in_sizes, int n_in,
                              void* d_out, int out_size, void* d_ws, size_t ws_size,
                              hipStream_t stream) {
    const float* x      = (const float*)d_in[0];
    const float* freqs  = (const float*)d_in[1];
    const int*   pos    = (const int*)d_in[2];
    const float* Wqkv   = (const float*)d_in[3];
    const float* bqkv   = (const float*)d_in[4];
    const float* Wdense = (const float*)d_in[5];
    const float* bdense = (const float*)d_in[6];
    float* out = (float*)d_out;

    // f32 region: qb, kb, vb [H,S,HD], ctx [S,D]  (64 MiB)
    float* qb  = (float*)d_ws;
    float* kb  = qb + (size_t)H * S * HD;
    float* vb  = kb + (size_t)H * S * HD;
    float* ctx = vb + (size_t)H * S * HD;

    const size_t nSD = (size_t)S * D;           // 4 Mi elems
    const size_t needed =
        4 * nSD * 4 +                            // qb,kb,vb,ctx f32
        4 * nSD * 2 +                            // xh,xl,ctxh,ctxl bf16
        2 * (size_t)D * N3 * 2 +                 // Wqkv_t hi/lo bf16
        2 * nSD * 2;                             // Wdense_t hi/lo bf16

    if (ws_size >= needed) {
        ushort_t* xh   = (ushort_t*)(ctx + nSD);
        ushort_t* xl   = xh + nSD;
        ushort_t* ctxh = xl + nSD;
        ushort_t* ctxl = ctxh + nSD;
        ushort_t* Wth  = ctxl + nSD;
        ushort_t* Wtl  = Wth + (size_t)D * N3;
        ushort_t* Wdth = Wtl + (size_t)D * N3;
        ushort_t* Wdtl = Wdth + nSD;

        convert_split_kernel<<<nSD / 4 / 256, 256, 0, stream>>>(x, xh, xl);
        dim3 gt1(D / 32, N3 / 32);
        convert_split_t_kernel<<<gt1, 256, 0, stream>>>(Wqkv, Wth, Wtl, D, N3);
        dim3 gt2(D / 32, D / 32);
        convert_split_t_kernel<<<gt2, 256, 0, stream>>>(Wdense, Wdth, Wdtl, D, D);

        dim3 g1(N3 / 128, S / 128);
        gemm_qkv_mfma<<<g1, 256, 0, stream>>>(xh, xl, Wth, Wtl, bqkv, freqs,
                                              pos, qb, kb, vb);
        dim3 g2(16, H);
        attn_kernel<<<g2, 256, 0, stream>>>(qb, kb, vb, ctx);

        convert_split_kernel<<<nSD / 4 / 256, 256, 0, stream>>>(ctx, ctxh, ctxl);
        dim3 g3(D / 128, S / 128);
        gemm_dense_mfma<<<g3, 256, 0, stream>>>(ctxh, ctxl, Wdth, Wdtl, bdense, out);
    } else {
        // fallback: R2 f32 path (needs only 64 MiB)
        dim3 g1(N3 / 64, S / 64);
        gemm_qkv_kernel<<<g1, 256, 0, stream>>>(x, Wqkv, bqkv, freqs, pos, qb, kb, vb);
        dim3 g2(16, H);
        attn_kernel<<<g2, 256, 0, stream>>>(qb, kb, vb, ctx);
        dim3 g3(D / 64, S / 64);
        gemm_dense_kernel<<<g3, 256, 0, stream>>>(ctx, Wdense, bdense, out);
    }
}

// Round 5
// 696.361 us; speedup vs baseline: 8.1450x; 1.4229x over previous
//
#include <hip/hip_runtime.h>

#define S 2048
#define D 2048
#define H 16
#define HD 128
#define N3 6144  // 3*D

typedef __attribute__((ext_vector_type(8))) short bf16x8;
typedef __attribute__((ext_vector_type(4))) float f32x4;
typedef unsigned short ushort_t;
typedef unsigned int uint_t;

// ---------------------------------------------------------------------------
// bf16 split helpers (round-to-nearest-even)
// ---------------------------------------------------------------------------
__device__ __forceinline__ ushort_t bf16_rne(float f) {
    uint_t u = __float_as_uint(f);
    u += 0x7fffu + ((u >> 16) & 1u);
    return (ushort_t)(u >> 16);
}
__device__ __forceinline__ float bf16_f32(ushort_t h) {
    return __uint_as_float(((uint_t)h) << 16);
}

// split f32 row-major -> hi/lo bf16 row-major (same layout)
__global__ __launch_bounds__(256) void convert_split_kernel(
    const float* __restrict__ in, ushort_t* __restrict__ hi,
    ushort_t* __restrict__ lo)
{
    const int i = blockIdx.x * 256 + threadIdx.x;  // per float4
    float4 v = ((const float4*)in)[i];
    ushort_t h0 = bf16_rne(v.x), h1 = bf16_rne(v.y);
    ushort_t h2 = bf16_rne(v.z), h3 = bf16_rne(v.w);
    ushort4 hv = make_ushort4(h0, h1, h2, h3);
    ushort4 lv = make_ushort4(bf16_rne(v.x - bf16_f32(h0)),
                              bf16_rne(v.y - bf16_f32(h1)),
                              bf16_rne(v.z - bf16_f32(h2)),
                              bf16_rne(v.w - bf16_f32(h3)));
    ((ushort4*)hi)[i] = hv;
    ((ushort4*)lo)[i] = lv;
}

// W [K][N] f32 -> Wt hi/lo [N][K] bf16 (transpose + split), 32x32 tiles
__global__ __launch_bounds__(256) void convert_split_t_kernel(
    const float* __restrict__ in, ushort_t* __restrict__ hi,
    ushort_t* __restrict__ lo, int Kdim, int Ndim)
{
    __shared__ float tile[32][33];
    const int k0 = blockIdx.x * 32, n0 = blockIdx.y * 32;
    const int tx = threadIdx.x & 31, ty = threadIdx.x >> 5;  // ty 0..7
    #pragma unroll
    for (int r = 0; r < 4; r++)
        tile[ty + r * 8][tx] = in[(size_t)(k0 + ty + r * 8) * Ndim + n0 + tx];
    __syncthreads();
    #pragma unroll
    for (int r = 0; r < 4; r++) {
        const int n = n0 + ty + r * 8;
        const int k = k0 + tx;
        float v = tile[tx][ty + r * 8];
        ushort_t h = bf16_rne(v);
        hi[(size_t)n * Kdim + k] = h;
        lo[(size_t)n * Kdim + k] = bf16_rne(v - bf16_f32(h));
    }
}

// ---------------------------------------------------------------------------
// async global->LDS, 16 B per lane, wave-uniform LDS base (HW adds lane*16).
// ---------------------------------------------------------------------------
__device__ __forceinline__ void gload16(const ushort_t* g, ushort_t* l) {
    __builtin_amdgcn_global_load_lds(
        (const __attribute__((address_space(1))) unsigned int*)g,
        (__attribute__((address_space(3))) unsigned int*)l, 16, 0, 0);
}

// ---------------------------------------------------------------------------
// Split-bf16 MFMA GEMM core (R4, verified): 128x128 tile, BK=32, 4 waves,
// 3-term (Ah*Bh + Ah*Bl + Al*Bh), staging via global_load_lds.
// ---------------------------------------------------------------------------
#define BK 32
#define TILE_ELEMS (128 * BK)

__device__ __forceinline__ void mm_core_split(
    const ushort_t* __restrict__ Agh, const ushort_t* __restrict__ Agl,
    const ushort_t* __restrict__ Bgh, const ushort_t* __restrict__ Bgl,
    const int K, ushort_t* lds, const int t, f32x4 (&acc)[4][4])
{
    ushort_t* As_h = lds;
    ushort_t* As_l = lds + TILE_ELEMS;
    ushort_t* Bs_h = lds + 2 * TILE_ELEMS;
    ushort_t* Bs_l = lds + 3 * TILE_ELEMS;

    const int lane = t & 63;
    const int wv   = t >> 6;
    const int lrow = lane >> 2;
    const int lk   = (lane & 3) * 8;
    const int quad = lane >> 4;
    const int lr   = lane & 15;
    const int wm   = (wv & 1) * 64;
    const int wn   = (wv >> 1) * 64;

    const int r0  = wv * 16;
    const int lo0 = r0 * BK;
    const int lo1 = (r0 + 64) * BK;

    for (int k0 = 0; k0 < K; k0 += BK) {
        __syncthreads();
        const size_t go0 = (size_t)(r0 + lrow) * K + k0 + lk;
        const size_t go1 = (size_t)(r0 + 64 + lrow) * K + k0 + lk;
        gload16(Agh + go0, As_h + lo0);
        gload16(Agh + go1, As_h + lo1);
        gload16(Agl + go0, As_l + lo0);
        gload16(Agl + go1, As_l + lo1);
        gload16(Bgh + go0, Bs_h + lo0);
        gload16(Bgh + go1, Bs_h + lo1);
        gload16(Bgl + go0, Bs_l + lo0);
        gload16(Bgl + go1, Bs_l + lo1);
        __syncthreads();

        bf16x8 af_h[4], af_l[4], bf_h[4], bf_l[4];
        #pragma unroll
        for (int i = 0; i < 4; i++) {
            af_h[i] = *(const bf16x8*)&As_h[(wm + i * 16 + lr) * BK + quad * 8];
            af_l[i] = *(const bf16x8*)&As_l[(wm + i * 16 + lr) * BK + quad * 8];
            bf_h[i] = *(const bf16x8*)&Bs_h[(wn + i * 16 + lr) * BK + quad * 8];
            bf_l[i] = *(const bf16x8*)&Bs_l[(wn + i * 16 + lr) * BK + quad * 8];
        }
        #pragma unroll
        for (int mt = 0; mt < 4; mt++)
            #pragma unroll
            for (int nt = 0; nt < 4; nt++) {
                acc[mt][nt] = __builtin_amdgcn_mfma_f32_16x16x32_bf16(
                    af_h[mt], bf_h[nt], acc[mt][nt], 0, 0, 0);
                acc[mt][nt] = __builtin_amdgcn_mfma_f32_16x16x32_bf16(
                    af_h[mt], bf_l[nt], acc[mt][nt], 0, 0, 0);
                acc[mt][nt] = __builtin_amdgcn_mfma_f32_16x16x32_bf16(
                    af_l[mt], bf_h[nt], acc[mt][nt], 0, 0, 0);
            }
    }
}

// ---------------------------------------------------------------------------
// QKV GEMM (MFMA) with split-bf16 outputs for the MFMA attention:
//   qh/ql, kh/kl: [H][S][HD] (RoPE applied; k scattered by input_pos)
//   vth/vtl:     [H][HD][S] (transposed for PV B-fragments; scattered)
// ---------------------------------------------------------------------------
__global__ __launch_bounds__(256) void gemm_qkv_mfma(
    const ushort_t* __restrict__ xh, const ushort_t* __restrict__ xl,
    const ushort_t* __restrict__ Wth, const ushort_t* __restrict__ Wtl,
    const float* __restrict__ bias, const float* __restrict__ freqs,
    const int* __restrict__ input_pos,
    ushort_t* __restrict__ qhg, ushort_t* __restrict__ qlg,
    ushort_t* __restrict__ khg, ushort_t* __restrict__ klg,
    ushort_t* __restrict__ vhg, ushort_t* __restrict__ vlg)
{
    __shared__ ushort_t lds[4 * TILE_ELEMS];
    const int t = threadIdx.x;
    const int col0 = blockIdx.x * 128;
    const int row0 = blockIdx.y * 128;

    f32x4 acc[4][4] = {};
    mm_core_split(xh + (size_t)row0 * D, xl + (size_t)row0 * D,
                  Wth + (size_t)col0 * D, Wtl + (size_t)col0 * D,
                  D, lds, t, acc);

    const int lane = t & 63;
    const int quad = lane >> 4;
    const int lr   = lane & 15;
    const int wm = ((t >> 6) & 1) * 64;
    const int wn = ((t >> 6) >> 1) * 64;

    const int which = col0 >> 11;           // 0=q 1=k 2=v
    const int hh = (col0 & 2047) >> 7;

    if (which == 2) {
        ushort_t* vh_b = vhg + (size_t)hh * HD * S;
        ushort_t* vl_b = vlg + (size_t)hh * HD * S;
        #pragma unroll
        for (int nt = 0; nt < 4; nt++) {
            const int d = wn + nt * 16 + lr;
            const float bsc = bias[col0 + d];
            #pragma unroll
            for (int mt = 0; mt < 4; mt++) {
                #pragma unroll
                for (int reg = 0; reg < 4; reg++) {
                    const int m = row0 + wm + mt * 16 + quad * 4 + reg;
                    const float v = acc[mt][nt][reg] + bsc;
                    const ushort_t hv = bf16_rne(v);
                    const ushort_t lv = bf16_rne(v - bf16_f32(hv));
                    const int pos = input_pos[m];
                    vh_b[(size_t)d * S + pos] = hv;
                    vl_b[(size_t)d * S + pos] = lv;
                }
            }
        }
    } else {
        ushort_t* oh_b = ((which == 0) ? qhg : khg) + (size_t)hh * S * HD;
        ushort_t* ol_b = ((which == 0) ? qlg : klg) + (size_t)hh * S * HD;
        #pragma unroll
        for (int nt = 0; nt < 4; nt++) {
            const int d = wn + nt * 16 + lr;
            const float bsc = bias[col0 + d];
            #pragma unroll
            for (int mt = 0; mt < 4; mt++) {
                #pragma unroll
                for (int reg = 0; reg < 4; reg++) {
                    const int m = row0 + wm + mt * 16 + quad * 4 + reg;
                    const float v = acc[mt][nt][reg] + bsc;
                    const float* fc = &freqs[((size_t)m * 64 + (d >> 1)) * 2];
                    const float c = fc[0], s = fc[1];
                    const float p = __shfl_xor(v, 1);
                    const float o = (d & 1) ? (v * c + p * s) : (v * c - p * s);
                    const ushort_t hv = bf16_rne(o);
                    const ushort_t lv = bf16_rne(o - bf16_f32(hv));
                    const int hp = __shfl_xor((int)hv, 1);
                    const int lp = __shfl_xor((int)lv, 1);
                    if (!(d & 1)) {
                        const int srow = (which == 0) ? m : input_pos[m];
                        *(uint_t*)&oh_b[(size_t)srow * HD + d] =
                            (uint_t)hv | ((uint_t)hp << 16);
                        *(uint_t*)&ol_b[(size_t)srow * HD + d] =
                            (uint_t)lv | ((uint_t)lp << 16);
                    }
                }
            }
        }
    }
}

// ---------------------------------------------------------------------------
// MFMA flash attention. Grid (32, 16), r = 31-bx (LPT order). Block = 256
// threads = 4 waves; BQ=64 (wave owns 16 q-rows), 32-key tiles.
// QK^T: 3-term split bf16; PV: P(bf16) * (Vh + Vl) 2-term.
// Row softmax stats in registers (C-layout rows are quad-local).
// P transits LDS (A-frag layout). 2 barriers per tile. Output: split-bf16
// ctxh/ctxl [S][D] directly (feeds dense MFMA GEMM with no conversion).
// ---------------------------------------------------------------------------
__global__ __launch_bounds__(256, 2) void attn_mfma_kernel(
    const ushort_t* __restrict__ qhg, const ushort_t* __restrict__ qlg,
    const ushort_t* __restrict__ khg, const ushort_t* __restrict__ klg,
    const ushort_t* __restrict__ vhg, const ushort_t* __restrict__ vlg,
    ushort_t* __restrict__ ctxh, ushort_t* __restrict__ ctxl)
{
    __shared__ ushort_t Kh_s[32 * 128];
    __shared__ ushort_t Kl_s[32 * 128];
    __shared__ ushort_t Vh_s[128 * 32];
    __shared__ ushort_t Vl_s[128 * 32];
    __shared__ ushort_t Ps[64 * 32];

    const int r = 31 - blockIdx.x;          // LPT: big blocks dispatch first
    const int h = blockIdx.y;
    const int q0 = r * 64;
    const int ntiles = 2 * r + 2;
    const int t = threadIdx.x;
    const int w = t >> 6, lane = t & 63;
    const int lr = lane & 15, quad = lane >> 4;

    // Q fragments (A-frag: m=lane&15, k=quad*8+j), rows q0 + w*16 + lr
    const size_t qrow = (size_t)h * S + q0 + w * 16 + lr;
    bf16x8 qf_h[4], qf_l[4];
    #pragma unroll
    for (int ks = 0; ks < 4; ks++) {
        qf_h[ks] = *(const bf16x8*)&qhg[qrow * HD + ks * 32 + quad * 8];
        qf_l[ks] = *(const bf16x8*)&qlg[qrow * HD + ks * 32 + quad * 8];
    }

    const ushort_t* kh_b = khg + (size_t)h * S * HD;
    const ushort_t* kl_b = klg + (size_t)h * S * HD;
    const ushort_t* vh_b = vhg + (size_t)h * HD * S;
    const ushort_t* vl_b = vlg + (size_t)h * HD * S;

    // staging lane offsets: K = 2 issues x 4 contiguous rows per wave;
    // V = 2 issues x 16 dims per wave (per-lane gather, stride S)
    const int vdim = lane >> 2;             // 0..15 within issue
    const int vkc  = (lane & 3) * 8;        // key chunk (elems)

    f32x4 O[8] = {};
    float mrow[4], lrow[4];
    #pragma unroll
    for (int rr = 0; rr < 4; rr++) { mrow[rr] = -1e30f; lrow[rr] = 0.f; }

    const float kSc = 0.08838834764831845f * 1.4426950408889634f; // scale*log2e

    for (int kt = 0; kt < ntiles; kt++) {
        const int k0 = kt * 32;
        __syncthreads();  // previous tile's PV done reading V

        #pragma unroll
        for (int j = 0; j < 2; j++) {
            const int krow = k0 + w * 8 + j * 4;
            gload16(kh_b + (size_t)krow * HD + lane * 8, Kh_s + (w * 8 + j * 4) * 128);
            gload16(kl_b + (size_t)krow * HD + lane * 8, Kl_s + (w * 8 + j * 4) * 128);
            const int dim = w * 32 + j * 16 + vdim;
            gload16(vh_b + (size_t)dim * S + k0 + vkc, Vh_s + (w * 32 + j * 16) * 32);
            gload16(vl_b + (size_t)dim * S + k0 + vkc, Vl_s + (w * 32 + j * 16) * 32);
        }
        __syncthreads();  // staged tile visible

        // ---- scores: 2 n-tiles of 16 keys, 4 k-steps, 3 terms
        f32x4 sa[2];
        #pragma unroll
        for (int nt = 0; nt < 2; nt++) {
            f32x4 s = {0.f, 0.f, 0.f, 0.f};
            #pragma unroll
            for (int ks = 0; ks < 4; ks++) {
                bf16x8 kf_h = *(const bf16x8*)&Kh_s[(nt * 16 + lr) * 128 + ks * 32 + quad * 8];
                bf16x8 kf_l = *(const bf16x8*)&Kl_s[(nt * 16 + lr) * 128 + ks * 32 + quad * 8];
                s = __builtin_amdgcn_mfma_f32_16x16x32_bf16(qf_h[ks], kf_h, s, 0, 0, 0);
                s = __builtin_amdgcn_mfma_f32_16x16x32_bf16(qf_l[ks], kf_h, s, 0, 0, 0);
                s = __builtin_amdgcn_mfma_f32_16x16x32_bf16(qf_h[ks], kf_l, s, 0, 0, 0);
            }
            sa[nt] = s;
        }

        // ---- online softmax (C-layout: row = quad*4+reg, col = nt*16+lr)
        const int rowbase = q0 + w * 16 + quad * 4;
        const bool need_mask = (k0 + 31) > (q0 + w * 16);
        float alpha[4], pv0[4], pv1[4];
        #pragma unroll
        for (int rr = 0; rr < 4; rr++) {
            float z0 = sa[0][rr] * kSc;
            float z1 = sa[1][rr] * kSc;
            if (need_mask) {
                const int rowg = rowbase + rr;
                if (k0 + lr > rowg)      z0 = -1e30f;
                if (k0 + 16 + lr > rowg) z1 = -1e30f;
            }
            float rm = fmaxf(z0, z1);
            #pragma unroll
            for (int off = 1; off < 16; off <<= 1)
                rm = fmaxf(rm, __shfl_xor(rm, off));
            const float nm = fmaxf(mrow[rr], rm);
            const float al = exp2f(mrow[rr] - nm);
            const float p0 = exp2f(z0 - nm);
            const float p1 = exp2f(z1 - nm);
            float ts = p0 + p1;
            #pragma unroll
            for (int off = 1; off < 16; off <<= 1)
                ts += __shfl_xor(ts, off);
            lrow[rr] = lrow[rr] * al + ts;
            mrow[rr] = nm;
            alpha[rr] = al;
            pv0[rr] = p0;
            pv1[rr] = p1;
        }

        // ---- P -> LDS as bf16 in A-frag source layout [qrow][key]
        #pragma unroll
        for (int rr = 0; rr < 4; rr++) {
            const int prow = (w * 16 + quad * 4 + rr) * 32;
            Ps[prow + lr]      = bf16_rne(pv0[rr]);
            Ps[prow + 16 + lr] = bf16_rne(pv1[rr]);
        }
        // no barrier: each wave reads only its own P rows (lgkmcnt orders)

        // ---- PV: O = O*alpha + P @ (Vh + Vl)
        #pragma unroll
        for (int nt = 0; nt < 8; nt++)
            #pragma unroll
            for (int rr = 0; rr < 4; rr++)
                O[nt][rr] *= alpha[rr];
        const bf16x8 pf = *(const bf16x8*)&Ps[(w * 16 + lr) * 32 + quad * 8];
        #pragma unroll
        for (int nt = 0; nt < 8; nt++) {
            bf16x8 vf_h = *(const bf16x8*)&Vh_s[(nt * 16 + lr) * 32 + quad * 8];
            bf16x8 vf_l = *(const bf16x8*)&Vl_s[(nt * 16 + lr) * 32 + quad * 8];
            O[nt] = __builtin_amdgcn_mfma_f32_16x16x32_bf16(pf, vf_h, O[nt], 0, 0, 0);
            O[nt] = __builtin_amdgcn_mfma_f32_16x16x32_bf16(pf, vf_l, O[nt], 0, 0, 0);
        }
    }

    // ---- epilogue: /l, split to bf16 hi/lo, store ctxh/ctxl [S][D]
    #pragma unroll
    for (int rr = 0; rr < 4; rr++) {
        const float inv = 1.0f / lrow[rr];
        const int qg = q0 + w * 16 + quad * 4 + rr;
        const size_t roff = (size_t)qg * D + h * HD;
        #pragma unroll
        for (int nt = 0; nt < 8; nt++) {
            const float o = O[nt][rr] * inv;
            const ushort_t hv = bf16_rne(o);
            const ushort_t lv = bf16_rne(o - bf16_f32(hv));
            const int hp = __shfl_xor((int)hv, 1);
            const int lp = __shfl_xor((int)lv, 1);
            if (!(lr & 1)) {
                *(uint_t*)&ctxh[roff + nt * 16 + lr] = (uint_t)hv | ((uint_t)hp << 16);
                *(uint_t*)&ctxl[roff + nt * 16 + lr] = (uint_t)lv | ((uint_t)lp << 16);
            }
        }
    }
}

// ---------------------------------------------------------------------------
// Dense GEMM (MFMA, unchanged core): out = ctx @ Wdense + b
// ---------------------------------------------------------------------------
__global__ __launch_bounds__(256) void gemm_dense_mfma(
    const ushort_t* __restrict__ Ah, const ushort_t* __restrict__ Al,
    const ushort_t* __restrict__ Wth, const ushort_t* __restrict__ Wtl,
    const float* __restrict__ bias, float* __restrict__ out)
{
    __shared__ ushort_t lds[4 * TILE_ELEMS];
    const int t = threadIdx.x;
    const int col0 = blockIdx.x * 128;
    const int row0 = blockIdx.y * 128;

    f32x4 acc[4][4] = {};
    mm_core_split(Ah + (size_t)row0 * D, Al + (size_t)row0 * D,
                  Wth + (size_t)col0 * D, Wtl + (size_t)col0 * D,
                  D, lds, t, acc);

    const int lane = t & 63;
    const int quad = lane >> 4;
    const int lr   = lane & 15;
    const int wm = ((t >> 6) & 1) * 64;
    const int wn = ((t >> 6) >> 1) * 64;

    #pragma unroll
    for (int nt = 0; nt < 4; nt++) {
        const int n = col0 + wn + nt * 16 + lr;
        const float bsc = bias[n];
        #pragma unroll
        for (int mt = 0; mt < 4; mt++) {
            #pragma unroll
            for (int reg = 0; reg < 4; reg++) {
                const int m = row0 + wm + mt * 16 + quad * 4 + reg;
                const float o = acc[mt][nt][reg] + bsc;
                const float po = __shfl_xor(o, 1);
                if (!(n & 1))
                    *(float2*)&out[(size_t)m * D + n] = make_float2(o, po);
            }
        }
    }
}

// ---------------------------------------------------------------------------
// Fallback f32 path (R2, known-good) for small workspace.
// ---------------------------------------------------------------------------
__global__ __launch_bounds__(256) void gemm_qkv_kernel(
    const float* __restrict__ x, const float* __restrict__ W,
    const float* __restrict__ bias, const float* __restrict__ freqs,
    const int* __restrict__ input_pos,
    float* __restrict__ qb, float* __restrict__ kb, float* __restrict__ vb)
{
    __shared__ float As[16][68];
    __shared__ float Bs[16][64];
    const int bx = blockIdx.x;
    const int by = blockIdx.y;
    const int tid = threadIdx.x;
    const int tx = tid & 15, ty = tid >> 4;
    const int row0 = by * 64, col0 = bx * 64;
    const int am = tid >> 2;
    const int ak = (tid & 3) * 4;
    const int bk = tid >> 4;
    const int bn = (tid & 15) * 4;
    float acc[4][4] = {};
    for (int k0 = 0; k0 < D; k0 += 16) {
        float4 av = *(const float4*)&x[(size_t)(row0 + am) * D + k0 + ak];
        float4 bv = *(const float4*)&W[(size_t)(k0 + bk) * N3 + col0 + bn];
        __syncthreads();
        As[ak + 0][am] = av.x; As[ak + 1][am] = av.y;
        As[ak + 2][am] = av.z; As[ak + 3][am] = av.w;
        *(float4*)&Bs[bk][bn] = bv;
        __syncthreads();
        #pragma unroll
        for (int k = 0; k < 16; k++) {
            float4 a4 = *(const float4*)&As[k][ty * 4];
            float4 b4 = *(const float4*)&Bs[k][tx * 4];
            float a[4] = {a4.x, a4.y, a4.z, a4.w};
            float b[4] = {b4.x, b4.y, b4.z, b4.w};
            #pragma unroll
            for (int r = 0; r < 4; r++)
                #pragma unroll
                for (int c = 0; c < 4; c++)
                    acc[r][c] += a[r] * b[c];
        }
    }
    const int j0 = col0 + tx * 4;
    const int which = j0 >> 11;
    const int hh = (j0 & 2047) >> 7;
    const int d0 = j0 & 127;
    const float bv0 = bias[j0 + 0], bv1 = bias[j0 + 1];
    const float bv2 = bias[j0 + 2], bv3 = bias[j0 + 3];
    #pragma unroll
    for (int r = 0; r < 4; r++) {
        const int grow = row0 + ty * 4 + r;
        float v0 = acc[r][0] + bv0, v1 = acc[r][1] + bv1;
        float v2 = acc[r][2] + bv2, v3 = acc[r][3] + bv3;
        if (which == 2) {
            const int pos = input_pos[grow];
            float4 o4 = make_float4(v0, v1, v2, v3);
            *(float4*)&vb[((size_t)hh * S + pos) * HD + d0] = o4;
        } else {
            const float* fc = &freqs[((size_t)grow * 64 + (d0 >> 1)) * 2];
            float c0 = fc[0], s0 = fc[1], c1 = fc[2], s1 = fc[3];
            float o0 = v0 * c0 - v1 * s0, o1 = v1 * c0 + v0 * s0;
            float o2 = v2 * c1 - v3 * s1, o3 = v3 * c1 + v2 * s1;
            float4 o4 = make_float4(o0, o1, o2, o3);
            if (which == 0) {
                *(float4*)&qb[((size_t)hh * S + grow) * HD + d0] = o4;
            } else {
                const int pos = input_pos[grow];
                *(float4*)&kb[((size_t)hh * S + pos) * HD + d0] = o4;
            }
        }
    }
}

#define BQ 64
#define ABK 32
#define QSTR 132
#define KVSTR 132
#define PSTR 68

__global__ __launch_bounds__(256) void attn_kernel(
    const float* __restrict__ qb, const float* __restrict__ kb,
    const float* __restrict__ vb, float* __restrict__ ctx)
{
    __shared__ float Qs[BQ * QSTR];
    __shared__ float KV[ABK * KVSTR];
    __shared__ float Psf[ABK * PSTR];

    const int pa = blockIdx.x;
    const int h  = blockIdx.y;
    const int t  = threadIdx.x;
    const int ty = t >> 4, tx = t & 15;
    const int i0  = ty * 4;
    const int j0  = tx * 2;
    const int dd0 = tx * 8;
    const int lr = t >> 3;
    const int lc = (t & 7) * 4;

    const float* kbase = kb + (size_t)h * S * HD;
    const float* vbase = vb + (size_t)h * S * HD;
    const float kSc = 0.08838834764831845f * 1.4426950408889634f;

    for (int ph = 0; ph < 2; ph++) {
        const int r = (ph == 0) ? pa : 31 - pa;
        const int q0 = r * BQ;
        const int ntiles = 2 * r + 2;

        #pragma unroll
        for (int pp = 0; pp < 2; pp++) {
            const int iq = lr + pp * 32;
            const float* src = qb + ((size_t)h * S + q0 + iq) * HD;
            #pragma unroll
            for (int ch = 0; ch < 4; ch++)
                *(float4*)&Qs[iq * QSTR + lc + ch * 32] =
                    *(const float4*)&src[lc + ch * 32];
        }

        float O[4][8] = {};
        float m[4], l[4];
        #pragma unroll
        for (int rr = 0; rr < 4; rr++) { m[rr] = -1e30f; l[rr] = 0.f; }

        float4 kpref[4];
        #pragma unroll
        for (int ch = 0; ch < 4; ch++)
            kpref[ch] = *(const float4*)&kbase[(size_t)lr * HD + lc + ch * 32];

        __syncthreads();

        for (int kt = 0; kt < ntiles; kt++) {
            const int k0 = kt * ABK;

            #pragma unroll
            for (int ch = 0; ch < 4; ch++)
                *(float4*)&KV[lr * KVSTR + lc + ch * 32] = kpref[ch];
            __syncthreads();

            float4 vpref[4];
            #pragma unroll
            for (int ch = 0; ch < 4; ch++)
                vpref[ch] = *(const float4*)&vbase[(size_t)(k0 + lr) * HD + lc + ch * 32];

            float acc[4][2] = {};
            #pragma unroll 4
            for (int d0 = 0; d0 < HD; d0 += 4) {
                float4 ka = *(const float4*)&KV[(j0 + 0) * KVSTR + d0];
                float4 kb4 = *(const float4*)&KV[(j0 + 1) * KVSTR + d0];
                #pragma unroll
                for (int rr = 0; rr < 4; rr++) {
                    float4 q4 = *(const float4*)&Qs[(i0 + rr) * QSTR + d0];
                    acc[rr][0] += q4.x * ka.x + q4.y * ka.y + q4.z * ka.z + q4.w * ka.w;
                    acc[rr][1] += q4.x * kb4.x + q4.y * kb4.y + q4.z * kb4.z + q4.w * kb4.w;
                }
            }

            const bool need_mask = (k0 + ABK - 1) > q0;
            float p[4][2], alpha[4];
            #pragma unroll
            for (int rr = 0; rr < 4; rr++) {
                float z0 = acc[rr][0] * kSc;
                float z1 = acc[rr][1] * kSc;
                if (need_mask) {
                    if (k0 + j0 + 0 > q0 + i0 + rr) z0 = -1e30f;
                    if (k0 + j0 + 1 > q0 + i0 + rr) z1 = -1e30f;
                }
                float rmax = fmaxf(z0, z1);
                #pragma unroll
                for (int off = 1; off < 16; off <<= 1)
                    rmax = fmaxf(rmax, __shfl_xor(rmax, off, 16));
                const float nm = fmaxf(m[rr], rmax);
                alpha[rr] = exp2f(m[rr] - nm);
                p[rr][0] = exp2f(z0 - nm);
                p[rr][1] = exp2f(z1 - nm);
                float ts = p[rr][0] + p[rr][1];
                #pragma unroll
                for (int off = 1; off < 16; off <<= 1)
                    ts += __shfl_xor(ts, off, 16);
                l[rr] = l[rr] * alpha[rr] + ts;
                m[rr] = nm;
            }
            __syncthreads();

            #pragma unroll
            for (int ch = 0; ch < 4; ch++)
                *(float4*)&KV[lr * KVSTR + lc + ch * 32] = vpref[ch];
            *(float4*)&Psf[(j0 + 0) * PSTR + i0] =
                make_float4(p[0][0], p[1][0], p[2][0], p[3][0]);
            *(float4*)&Psf[(j0 + 1) * PSTR + i0] =
                make_float4(p[0][1], p[1][1], p[2][1], p[3][1]);
            if (kt + 1 < ntiles) {
                #pragma unroll
                for (int ch = 0; ch < 4; ch++)
                    kpref[ch] = *(const float4*)&kbase[(size_t)(k0 + ABK + lr) * HD + lc + ch * 32];
            }
            __syncthreads();

            #pragma unroll
            for (int rr = 0; rr < 4; rr++)
                #pragma unroll
                for (int c = 0; c < 8; c++)
                    O[rr][c] *= alpha[rr];
            #pragma unroll 4
            for (int j = 0; j < ABK; j++) {
                float4 pj = *(const float4*)&Psf[j * PSTR + i0];
                float4 v0 = *(const float4*)&KV[j * KVSTR + dd0];
                float4 v1 = *(const float4*)&KV[j * KVSTR + dd0 + 4];
                const float pr[4] = {pj.x, pj.y, pj.z, pj.w};
                const float vv[8] = {v0.x, v0.y, v0.z, v0.w, v1.x, v1.y, v1.z, v1.w};
                #pragma unroll
                for (int rr = 0; rr < 4; rr++)
                    #pragma unroll
                    for (int c = 0; c < 8; c++)
                        O[rr][c] += pr[rr] * vv[c];
            }
            __syncthreads();
        }

        #pragma unroll
        for (int rr = 0; rr < 4; rr++) {
            const float inv = 1.0f / l[rr];
            const int qg = q0 + i0 + rr;
            float4 o0 = make_float4(O[rr][0] * inv, O[rr][1] * inv,
                                    O[rr][2] * inv, O[rr][3] * inv);
            float4 o1 = make_float4(O[rr][4] * inv, O[rr][5] * inv,
                                    O[rr][6] * inv, O[rr][7] * inv);
            float* dst = &ctx[((size_t)qg * H + h) * HD + dd0];
            *(float4*)&dst[0] = o0;
            *(float4*)&dst[4] = o1;
        }
        __syncthreads();
    }
}

__global__ __launch_bounds__(256) void gemm_dense_kernel(
    const float* __restrict__ A, const float* __restrict__ W,
    const float* __restrict__ bias, float* __restrict__ out)
{
    __shared__ float As[16][68];
    __shared__ float Bs[16][64];
    const int bx = blockIdx.x;
    const int by = blockIdx.y;
    const int tid = threadIdx.x;
    const int tx = tid & 15, ty = tid >> 4;
    const int row0 = by * 64, col0 = bx * 64;
    const int am = tid >> 2;
    const int ak = (tid & 3) * 4;
    const int bk = tid >> 4;
    const int bn = (tid & 15) * 4;
    float acc[4][4] = {};
    for (int k0 = 0; k0 < D; k0 += 16) {
        float4 av = *(const float4*)&A[(size_t)(row0 + am) * D + k0 + ak];
        float4 bv = *(const float4*)&W[(size_t)(k0 + bk) * D + col0 + bn];
        __syncthreads();
        As[ak + 0][am] = av.x; As[ak + 1][am] = av.y;
        As[ak + 2][am] = av.z; As[ak + 3][am] = av.w;
        *(float4*)&Bs[bk][bn] = bv;
        __syncthreads();
        #pragma unroll
        for (int k = 0; k < 16; k++) {
            float4 a4 = *(const float4*)&As[k][ty * 4];
            float4 b4 = *(const float4*)&Bs[k][tx * 4];
            float a[4] = {a4.x, a4.y, a4.z, a4.w};
            float b[4] = {b4.x, b4.y, b4.z, b4.w};
            #pragma unroll
            for (int r = 0; r < 4; r++)
                #pragma unroll
                for (int c = 0; c < 4; c++)
                    acc[r][c] += a[r] * b[c];
        }
    }
    const int j0 = col0 + tx * 4;
    const float bv0 = bias[j0 + 0], bv1 = bias[j0 + 1];
    const float bv2 = bias[j0 + 2], bv3 = bias[j0 + 3];
    #pragma unroll
    for (int r = 0; r < 4; r++) {
        const int grow = row0 + ty * 4 + r;
        float4 o4 = make_float4(acc[r][0] + bv0, acc[r][1] + bv1,
                                acc[r][2] + bv2, acc[r][3] + bv3);
        *(float4*)&out[(size_t)grow * D + j0] = o4;
    }
}

extern "C" void kernel_launch(void* const* d_in, const int* in_sizes, int n_in,
                              void* d_out, int out_size, void* d_ws, size_t ws_size,
                              hipStream_t stream) {
    const float* x      = (const float*)d_in[0];
    const float* freqs  = (const float*)d_in[1];
    const int*   pos    = (const int*)d_in[2];
    const float* Wqkv   = (const float*)d_in[3];
    const float* bqkv   = (const float*)d_in[4];
    const float* Wdense = (const float*)d_in[5];
    const float* bdense = (const float*)d_in[6];
    float* out = (float*)d_out;

    const size_t nSD = (size_t)S * D;   // 4 Mi elems
    const size_t nW1 = (size_t)D * N3;  // 12 Mi elems

    // mfma path ws (all bf16 ushort): q/k hi+lo, vt hi+lo, ctx hi+lo,
    // x hi+lo, Wqkv_t hi+lo, Wdense_t hi+lo  -> 144 MiB
    const size_t needed = (10 * nSD + 2 * nW1) * sizeof(ushort_t);

    if (ws_size >= needed) {
        ushort_t* qh   = (ushort_t*)d_ws;
        ushort_t* ql   = qh + nSD;
        ushort_t* kh   = ql + nSD;
        ushort_t* kl   = kh + nSD;
        ushort_t* vh   = kl + nSD;
        ushort_t* vl   = vh + nSD;
        ushort_t* ctxh = vl + nSD;
        ushort_t* ctxl = ctxh + nSD;
        ushort_t* xh   = ctxl + nSD;
        ushort_t* xl   = xh + nSD;
        ushort_t* Wth  = xl + nSD;
        ushort_t* Wtl  = Wth + nW1;
        ushort_t* Wdth = Wtl + nW1;
        ushort_t* Wdtl = Wdth + nSD;
        // Wdtl + nSD <= 10*nSD + 2*nW1 ✓ (uses 12*nSD + 2*nW1? no:
        // layout above = 10 nSD-arrays + 2 nW1 + ... recount: qh..xl = 10*nSD;
        // Wth,Wtl = 2*nW1; Wdth,Wdtl = 2*nSD -> total 12*nSD + 2*nW1.
        (void)0;

        convert_split_kernel<<<nSD / 4 / 256, 256, 0, stream>>>(x, xh, xl);
        dim3 gt1(D / 32, N3 / 32);
        convert_split_t_kernel<<<gt1, 256, 0, stream>>>(Wqkv, Wth, Wtl, D, N3);
        dim3 gt2(D / 32, D / 32);
        convert_split_t_kernel<<<gt2, 256, 0, stream>>>(Wdense, Wdth, Wdtl, D, D);

        dim3 g1(N3 / 128, S / 128);
        gemm_qkv_mfma<<<g1, 256, 0, stream>>>(xh, xl, Wth, Wtl, bqkv, freqs,
                                              pos, qh, ql, kh, kl, vh, vl);
        dim3 g2(32, H);
        attn_mfma_kernel<<<g2, 256, 0, stream>>>(qh, ql, kh, kl, vh, vl,
                                                 ctxh, ctxl);
        dim3 g3(D / 128, S / 128);
        gemm_dense_mfma<<<g3, 256, 0, stream>>>(ctxh, ctxl, Wdth, Wdtl, bdense, out);
    } else {
        // fallback: R2 f32 path (needs only 64 MiB)
        float* qb  = (float*)d_ws;
        float* kb  = qb + (size_t)H * S * HD;
        float* vb  = kb + (size_t)H * S * HD;
        float* ctx = vb + (size_t)H * S * HD;
        dim3 g1(N3 / 64, S / 64);
        gemm_qkv_kernel<<<g1, 256, 0, stream>>>(x, Wqkv, bqkv, freqs, pos, qb, kb, vb);
        dim3 g2(16, H);
        attn_kernel<<<g2, 256, 0, stream>>>(qb, kb, vb, ctx);
        dim3 g3(D / 64, S / 64);
        gemm_dense_kernel<<<g3, 256, 0, stream>>>(ctx, Wdense, bdense, out);
    }
}

// Round 6
// 600.719 us; speedup vs baseline: 9.4418x; 1.1592x over previous
//
#include <hip/hip_runtime.h>

#define S 2048
#define D 2048
#define H 16
#define HD 128
#define N3 6144  // 3*D

typedef __attribute__((ext_vector_type(8))) short bf16x8;
typedef __attribute__((ext_vector_type(4))) float f32x4;
typedef unsigned short ushort_t;
typedef unsigned int uint_t;

// ---------------------------------------------------------------------------
// bf16 split helpers (round-to-nearest-even)
// ---------------------------------------------------------------------------
__device__ __forceinline__ ushort_t bf16_rne(float f) {
    uint_t u = __float_as_uint(f);
    u += 0x7fffu + ((u >> 16) & 1u);
    return (ushort_t)(u >> 16);
}
__device__ __forceinline__ float bf16_f32(ushort_t h) {
    return __uint_as_float(((uint_t)h) << 16);
}

// split f32 row-major -> hi/lo bf16 row-major (same layout)
__global__ __launch_bounds__(256) void convert_split_kernel(
    const float* __restrict__ in, ushort_t* __restrict__ hi,
    ushort_t* __restrict__ lo)
{
    const int i = blockIdx.x * 256 + threadIdx.x;  // per float4
    float4 v = ((const float4*)in)[i];
    ushort_t h0 = bf16_rne(v.x), h1 = bf16_rne(v.y);
    ushort_t h2 = bf16_rne(v.z), h3 = bf16_rne(v.w);
    ushort4 hv = make_ushort4(h0, h1, h2, h3);
    ushort4 lv = make_ushort4(bf16_rne(v.x - bf16_f32(h0)),
                              bf16_rne(v.y - bf16_f32(h1)),
                              bf16_rne(v.z - bf16_f32(h2)),
                              bf16_rne(v.w - bf16_f32(h3)));
    ((ushort4*)hi)[i] = hv;
    ((ushort4*)lo)[i] = lv;
}

// W [K][N] f32 -> Wt hi/lo [N][K] bf16 (transpose + split), 32x32 tiles
__global__ __launch_bounds__(256) void convert_split_t_kernel(
    const float* __restrict__ in, ushort_t* __restrict__ hi,
    ushort_t* __restrict__ lo, int Kdim, int Ndim)
{
    __shared__ float tile[32][33];
    const int k0 = blockIdx.x * 32, n0 = blockIdx.y * 32;
    const int tx = threadIdx.x & 31, ty = threadIdx.x >> 5;  // ty 0..7
    #pragma unroll
    for (int r = 0; r < 4; r++)
        tile[ty + r * 8][tx] = in[(size_t)(k0 + ty + r * 8) * Ndim + n0 + tx];
    __syncthreads();
    #pragma unroll
    for (int r = 0; r < 4; r++) {
        const int n = n0 + ty + r * 8;
        const int k = k0 + tx;
        float v = tile[tx][ty + r * 8];
        ushort_t h = bf16_rne(v);
        hi[(size_t)n * Kdim + k] = h;
        lo[(size_t)n * Kdim + k] = bf16_rne(v - bf16_f32(h));
    }
}

// ---------------------------------------------------------------------------
// async global->LDS, 16 B per lane, wave-uniform LDS base (HW adds lane*16).
// ---------------------------------------------------------------------------
__device__ __forceinline__ void gload16(const ushort_t* g, ushort_t* l) {
    __builtin_amdgcn_global_load_lds(
        (const __attribute__((address_space(1))) unsigned int*)g,
        (__attribute__((address_space(3))) unsigned int*)l, 16, 0, 0);
}

// ---------------------------------------------------------------------------
// Split-bf16 MFMA GEMM core (R4, verified): 128x128 tile, BK=32, 4 waves,
// 3-term (Ah*Bh + Ah*Bl + Al*Bh), staging via global_load_lds.
// ---------------------------------------------------------------------------
#define BK 32
#define TILE_ELEMS (128 * BK)

__device__ __forceinline__ void mm_core_split(
    const ushort_t* __restrict__ Agh, const ushort_t* __restrict__ Agl,
    const ushort_t* __restrict__ Bgh, const ushort_t* __restrict__ Bgl,
    const int K, ushort_t* lds, const int t, f32x4 (&acc)[4][4])
{
    ushort_t* As_h = lds;
    ushort_t* As_l = lds + TILE_ELEMS;
    ushort_t* Bs_h = lds + 2 * TILE_ELEMS;
    ushort_t* Bs_l = lds + 3 * TILE_ELEMS;

    const int lane = t & 63;
    const int wv   = t >> 6;
    const int lrow = lane >> 2;
    const int lk   = (lane & 3) * 8;
    const int quad = lane >> 4;
    const int lr   = lane & 15;
    const int wm   = (wv & 1) * 64;
    const int wn   = (wv >> 1) * 64;

    const int r0  = wv * 16;
    const int lo0 = r0 * BK;
    const int lo1 = (r0 + 64) * BK;

    for (int k0 = 0; k0 < K; k0 += BK) {
        __syncthreads();
        const size_t go0 = (size_t)(r0 + lrow) * K + k0 + lk;
        const size_t go1 = (size_t)(r0 + 64 + lrow) * K + k0 + lk;
        gload16(Agh + go0, As_h + lo0);
        gload16(Agh + go1, As_h + lo1);
        gload16(Agl + go0, As_l + lo0);
        gload16(Agl + go1, As_l + lo1);
        gload16(Bgh + go0, Bs_h + lo0);
        gload16(Bgh + go1, Bs_h + lo1);
        gload16(Bgl + go0, Bs_l + lo0);
        gload16(Bgl + go1, Bs_l + lo1);
        __syncthreads();

        bf16x8 af_h[4], af_l[4], bf_h[4], bf_l[4];
        #pragma unroll
        for (int i = 0; i < 4; i++) {
            af_h[i] = *(const bf16x8*)&As_h[(wm + i * 16 + lr) * BK + quad * 8];
            af_l[i] = *(const bf16x8*)&As_l[(wm + i * 16 + lr) * BK + quad * 8];
            bf_h[i] = *(const bf16x8*)&Bs_h[(wn + i * 16 + lr) * BK + quad * 8];
            bf_l[i] = *(const bf16x8*)&Bs_l[(wn + i * 16 + lr) * BK + quad * 8];
        }
        #pragma unroll
        for (int mt = 0; mt < 4; mt++)
            #pragma unroll
            for (int nt = 0; nt < 4; nt++) {
                acc[mt][nt] = __builtin_amdgcn_mfma_f32_16x16x32_bf16(
                    af_h[mt], bf_h[nt], acc[mt][nt], 0, 0, 0);
                acc[mt][nt] = __builtin_amdgcn_mfma_f32_16x16x32_bf16(
                    af_h[mt], bf_l[nt], acc[mt][nt], 0, 0, 0);
                acc[mt][nt] = __builtin_amdgcn_mfma_f32_16x16x32_bf16(
                    af_l[mt], bf_h[nt], acc[mt][nt], 0, 0, 0);
            }
    }
}

// ---------------------------------------------------------------------------
// QKV GEMM (MFMA) with split-bf16 outputs (unchanged from R5).
// ---------------------------------------------------------------------------
__global__ __launch_bounds__(256) void gemm_qkv_mfma(
    const ushort_t* __restrict__ xh, const ushort_t* __restrict__ xl,
    const ushort_t* __restrict__ Wth, const ushort_t* __restrict__ Wtl,
    const float* __restrict__ bias, const float* __restrict__ freqs,
    const int* __restrict__ input_pos,
    ushort_t* __restrict__ qhg, ushort_t* __restrict__ qlg,
    ushort_t* __restrict__ khg, ushort_t* __restrict__ klg,
    ushort_t* __restrict__ vhg, ushort_t* __restrict__ vlg)
{
    __shared__ ushort_t lds[4 * TILE_ELEMS];
    const int t = threadIdx.x;
    const int col0 = blockIdx.x * 128;
    const int row0 = blockIdx.y * 128;

    f32x4 acc[4][4] = {};
    mm_core_split(xh + (size_t)row0 * D, xl + (size_t)row0 * D,
                  Wth + (size_t)col0 * D, Wtl + (size_t)col0 * D,
                  D, lds, t, acc);

    const int lane = t & 63;
    const int quad = lane >> 4;
    const int lr   = lane & 15;
    const int wm = ((t >> 6) & 1) * 64;
    const int wn = ((t >> 6) >> 1) * 64;

    const int which = col0 >> 11;           // 0=q 1=k 2=v
    const int hh = (col0 & 2047) >> 7;

    if (which == 2) {
        ushort_t* vh_b = vhg + (size_t)hh * HD * S;
        ushort_t* vl_b = vlg + (size_t)hh * HD * S;
        #pragma unroll
        for (int nt = 0; nt < 4; nt++) {
            const int d = wn + nt * 16 + lr;
            const float bsc = bias[col0 + d];
            #pragma unroll
            for (int mt = 0; mt < 4; mt++) {
                #pragma unroll
                for (int reg = 0; reg < 4; reg++) {
                    const int m = row0 + wm + mt * 16 + quad * 4 + reg;
                    const float v = acc[mt][nt][reg] + bsc;
                    const ushort_t hv = bf16_rne(v);
                    const ushort_t lv = bf16_rne(v - bf16_f32(hv));
                    const int pos = input_pos[m];
                    vh_b[(size_t)d * S + pos] = hv;
                    vl_b[(size_t)d * S + pos] = lv;
                }
            }
        }
    } else {
        ushort_t* oh_b = ((which == 0) ? qhg : khg) + (size_t)hh * S * HD;
        ushort_t* ol_b = ((which == 0) ? qlg : klg) + (size_t)hh * S * HD;
        #pragma unroll
        for (int nt = 0; nt < 4; nt++) {
            const int d = wn + nt * 16 + lr;
            const float bsc = bias[col0 + d];
            #pragma unroll
            for (int mt = 0; mt < 4; mt++) {
                #pragma unroll
                for (int reg = 0; reg < 4; reg++) {
                    const int m = row0 + wm + mt * 16 + quad * 4 + reg;
                    const float v = acc[mt][nt][reg] + bsc;
                    const float* fc = &freqs[((size_t)m * 64 + (d >> 1)) * 2];
                    const float c = fc[0], s = fc[1];
                    const float p = __shfl_xor(v, 1);
                    const float o = (d & 1) ? (v * c + p * s) : (v * c - p * s);
                    const ushort_t hv = bf16_rne(o);
                    const ushort_t lv = bf16_rne(o - bf16_f32(hv));
                    const int hp = __shfl_xor((int)hv, 1);
                    const int lp = __shfl_xor((int)lv, 1);
                    if (!(d & 1)) {
                        const int srow = (which == 0) ? m : input_pos[m];
                        *(uint_t*)&oh_b[(size_t)srow * HD + d] =
                            (uint_t)hv | ((uint_t)hp << 16);
                        *(uint_t*)&ol_b[(size_t)srow * HD + d] =
                            (uint_t)lv | ((uint_t)lp << 16);
                    }
                }
            }
        }
    }
}

// ---------------------------------------------------------------------------
// MFMA flash attention, R6: double-buffered staging (1 barrier/tile),
// K in ks-major LDS layout [4][32 keys][32 elems] (64 B fragment stride,
// m97-benign banks), V [128 d][32 keys], anti-correlated load balance
// (r = bx for h>=8 else 31-bx  => every CU gets ~66 tiles).
// ---------------------------------------------------------------------------
__global__ __launch_bounds__(256, 2) void attn_mfma_kernel(
    const ushort_t* __restrict__ qhg, const ushort_t* __restrict__ qlg,
    const ushort_t* __restrict__ khg, const ushort_t* __restrict__ klg,
    const ushort_t* __restrict__ vhg, const ushort_t* __restrict__ vlg,
    ushort_t* __restrict__ ctxh, ushort_t* __restrict__ ctxl)
{
    __shared__ ushort_t Khs[2][4096];   // [buf][ks*1024 + key*32 + d8]
    __shared__ ushort_t Kls[2][4096];
    __shared__ ushort_t Vhs[2][4096];   // [buf][dim*32 + key8]
    __shared__ ushort_t Vls[2][4096];
    __shared__ ushort_t Ps[64 * 32];

    const int h = blockIdx.y;
    const int r = (h & 8) ? blockIdx.x : (31 - blockIdx.x);
    const int q0 = r * 64;
    const int ntiles = 2 * r + 2;
    const int t = threadIdx.x;
    const int w = t >> 6, lane = t & 63;
    const int lr = lane & 15, quad = lane >> 4;

    // Q fragments (A-frag: m=lane&15, k=quad*8+j), rows q0 + w*16 + lr
    const size_t qrow = (size_t)h * S + q0 + w * 16 + lr;
    bf16x8 qf_h[4], qf_l[4];
    #pragma unroll
    for (int ks = 0; ks < 4; ks++) {
        qf_h[ks] = *(const bf16x8*)&qhg[qrow * HD + ks * 32 + quad * 8];
        qf_l[ks] = *(const bf16x8*)&qlg[qrow * HD + ks * 32 + quad * 8];
    }

    const ushort_t* kh_b = khg + (size_t)h * S * HD;
    const ushort_t* kl_b = klg + (size_t)h * S * HD;
    const ushort_t* vh_b = vhg + (size_t)h * HD * S;
    const ushort_t* vl_b = vlg + (size_t)h * HD * S;

    const int keyq = lane >> 2;   // 0..15
    const int sub  = lane & 3;    // 16B chunk index

    // stage tile kt into buffer buf. Wave w stages K ks-chunk = w (both
    // 16-key halves, hi+lo) and V dims w*32..w*32+31 (hi+lo).
    auto stage = [&](int kt, int buf) {
        const int k0 = kt * 32;
        #pragma unroll
        for (int hf = 0; hf < 2; hf++) {
            const size_t ksrc = (size_t)(k0 + hf * 16 + keyq) * HD + w * 32 + sub * 8;
            gload16(kh_b + ksrc, &Khs[buf][w * 1024 + hf * 512]);
            gload16(kl_b + ksrc, &Kls[buf][w * 1024 + hf * 512]);
            const int dim = w * 32 + hf * 16 + keyq;
            const size_t vsrc = (size_t)dim * S + k0 + sub * 8;
            gload16(vh_b + vsrc, &Vhs[buf][(w * 32 + hf * 16) * 32]);
            gload16(vl_b + vsrc, &Vls[buf][(w * 32 + hf * 16) * 32]);
        }
    };

    f32x4 O[8] = {};
    float mrow[4], lrow[4];
    #pragma unroll
    for (int rr = 0; rr < 4; rr++) { mrow[rr] = -1e30f; lrow[rr] = 0.f; }

    const float kSc = 0.08838834764831845f * 1.4426950408889634f; // scale*log2e

    stage(0, 0);

    for (int kt = 0; kt < ntiles; kt++) {
        const int k0 = kt * 32;
        const int cur = kt & 1;
        __syncthreads();  // drains vmcnt -> tile kt visible; buf cur^1 free

        if (kt + 1 < ntiles) stage(kt + 1, cur ^ 1);

        // ---- scores: 2 n-tiles of 16 keys, 4 k-steps, 3 terms
        f32x4 sa[2];
        #pragma unroll
        for (int nt = 0; nt < 2; nt++) {
            f32x4 s = {0.f, 0.f, 0.f, 0.f};
            #pragma unroll
            for (int ks = 0; ks < 4; ks++) {
                bf16x8 kf_h = *(const bf16x8*)&Khs[cur][ks * 1024 + (nt * 16 + lr) * 32 + quad * 8];
                bf16x8 kf_l = *(const bf16x8*)&Kls[cur][ks * 1024 + (nt * 16 + lr) * 32 + quad * 8];
                s = __builtin_amdgcn_mfma_f32_16x16x32_bf16(qf_h[ks], kf_h, s, 0, 0, 0);
                s = __builtin_amdgcn_mfma_f32_16x16x32_bf16(qf_l[ks], kf_h, s, 0, 0, 0);
                s = __builtin_amdgcn_mfma_f32_16x16x32_bf16(qf_h[ks], kf_l, s, 0, 0, 0);
            }
            sa[nt] = s;
        }

        // ---- online softmax (C-layout: row = quad*4+reg, col = nt*16+lr)
        const int rowbase = q0 + w * 16 + quad * 4;
        const bool need_mask = (k0 + 31) > (q0 + w * 16);
        float alpha[4], pv0[4], pv1[4];
        #pragma unroll
        for (int rr = 0; rr < 4; rr++) {
            float z0 = sa[0][rr] * kSc;
            float z1 = sa[1][rr] * kSc;
            if (need_mask) {
                const int rowg = rowbase + rr;
                if (k0 + lr > rowg)      z0 = -1e30f;
                if (k0 + 16 + lr > rowg) z1 = -1e30f;
            }
            float rm = fmaxf(z0, z1);
            #pragma unroll
            for (int off = 1; off < 16; off <<= 1)
                rm = fmaxf(rm, __shfl_xor(rm, off));
            const float nm = fmaxf(mrow[rr], rm);
            const float al = exp2f(mrow[rr] - nm);
            const float p0 = exp2f(z0 - nm);
            const float p1 = exp2f(z1 - nm);
            float ts = p0 + p1;
            #pragma unroll
            for (int off = 1; off < 16; off <<= 1)
                ts += __shfl_xor(ts, off);
            lrow[rr] = lrow[rr] * al + ts;
            mrow[rr] = nm;
            alpha[rr] = al;
            pv0[rr] = p0;
            pv1[rr] = p1;
        }

        // ---- P -> LDS as bf16 in A-frag source layout [qrow][key]
        #pragma unroll
        for (int rr = 0; rr < 4; rr++) {
            const int prow = (w * 16 + quad * 4 + rr) * 32;
            Ps[prow + lr]      = bf16_rne(pv0[rr]);
            Ps[prow + 16 + lr] = bf16_rne(pv1[rr]);
        }
        // no barrier: each wave reads only its own P rows (lgkmcnt orders)

        // ---- PV: O = O*alpha + P @ (Vh + Vl)
        #pragma unroll
        for (int nt = 0; nt < 8; nt++)
            #pragma unroll
            for (int rr = 0; rr < 4; rr++)
                O[nt][rr] *= alpha[rr];
        const bf16x8 pf = *(const bf16x8*)&Ps[(w * 16 + lr) * 32 + quad * 8];
        #pragma unroll
        for (int nt = 0; nt < 8; nt++) {
            bf16x8 vf_h = *(const bf16x8*)&Vhs[cur][(nt * 16 + lr) * 32 + quad * 8];
            bf16x8 vf_l = *(const bf16x8*)&Vls[cur][(nt * 16 + lr) * 32 + quad * 8];
            O[nt] = __builtin_amdgcn_mfma_f32_16x16x32_bf16(pf, vf_h, O[nt], 0, 0, 0);
            O[nt] = __builtin_amdgcn_mfma_f32_16x16x32_bf16(pf, vf_l, O[nt], 0, 0, 0);
        }
    }

    // ---- epilogue: /l, split to bf16 hi/lo, store ctxh/ctxl [S][D]
    #pragma unroll
    for (int rr = 0; rr < 4; rr++) {
        const float inv = 1.0f / lrow[rr];
        const int qg = q0 + w * 16 + quad * 4 + rr;
        const size_t roff = (size_t)qg * D + h * HD;
        #pragma unroll
        for (int nt = 0; nt < 8; nt++) {
            const float o = O[nt][rr] * inv;
            const ushort_t hv = bf16_rne(o);
            const ushort_t lv = bf16_rne(o - bf16_f32(hv));
            const int hp = __shfl_xor((int)hv, 1);
            const int lp = __shfl_xor((int)lv, 1);
            if (!(lr & 1)) {
                *(uint_t*)&ctxh[roff + nt * 16 + lr] = (uint_t)hv | ((uint_t)hp << 16);
                *(uint_t*)&ctxl[roff + nt * 16 + lr] = (uint_t)lv | ((uint_t)lp << 16);
            }
        }
    }
}

// ---------------------------------------------------------------------------
// Dense GEMM (MFMA, unchanged): out = ctx @ Wdense + b
// ---------------------------------------------------------------------------
__global__ __launch_bounds__(256) void gemm_dense_mfma(
    const ushort_t* __restrict__ Ah, const ushort_t* __restrict__ Al,
    const ushort_t* __restrict__ Wth, const ushort_t* __restrict__ Wtl,
    const float* __restrict__ bias, float* __restrict__ out)
{
    __shared__ ushort_t lds[4 * TILE_ELEMS];
    const int t = threadIdx.x;
    const int col0 = blockIdx.x * 128;
    const int row0 = blockIdx.y * 128;

    f32x4 acc[4][4] = {};
    mm_core_split(Ah + (size_t)row0 * D, Al + (size_t)row0 * D,
                  Wth + (size_t)col0 * D, Wtl + (size_t)col0 * D,
                  D, lds, t, acc);

    const int lane = t & 63;
    const int quad = lane >> 4;
    const int lr   = lane & 15;
    const int wm = ((t >> 6) & 1) * 64;
    const int wn = ((t >> 6) >> 1) * 64;

    #pragma unroll
    for (int nt = 0; nt < 4; nt++) {
        const int n = col0 + wn + nt * 16 + lr;
        const float bsc = bias[n];
        #pragma unroll
        for (int mt = 0; mt < 4; mt++) {
            #pragma unroll
            for (int reg = 0; reg < 4; reg++) {
                const int m = row0 + wm + mt * 16 + quad * 4 + reg;
                const float o = acc[mt][nt][reg] + bsc;
                const float po = __shfl_xor(o, 1);
                if (!(n & 1))
                    *(float2*)&out[(size_t)m * D + n] = make_float2(o, po);
            }
        }
    }
}

// ---------------------------------------------------------------------------
// Fallback f32 path (R2, known-good) for small workspace.
// ---------------------------------------------------------------------------
__global__ __launch_bounds__(256) void gemm_qkv_kernel(
    const float* __restrict__ x, const float* __restrict__ W,
    const float* __restrict__ bias, const float* __restrict__ freqs,
    const int* __restrict__ input_pos,
    float* __restrict__ qb, float* __restrict__ kb, float* __restrict__ vb)
{
    __shared__ float As[16][68];
    __shared__ float Bs[16][64];
    const int bx = blockIdx.x;
    const int by = blockIdx.y;
    const int tid = threadIdx.x;
    const int tx = tid & 15, ty = tid >> 4;
    const int row0 = by * 64, col0 = bx * 64;
    const int am = tid >> 2;
    const int ak = (tid & 3) * 4;
    const int bk = tid >> 4;
    const int bn = (tid & 15) * 4;
    float acc[4][4] = {};
    for (int k0 = 0; k0 < D; k0 += 16) {
        float4 av = *(const float4*)&x[(size_t)(row0 + am) * D + k0 + ak];
        float4 bv = *(const float4*)&W[(size_t)(k0 + bk) * N3 + col0 + bn];
        __syncthreads();
        As[ak + 0][am] = av.x; As[ak + 1][am] = av.y;
        As[ak + 2][am] = av.z; As[ak + 3][am] = av.w;
        *(float4*)&Bs[bk][bn] = bv;
        __syncthreads();
        #pragma unroll
        for (int k = 0; k < 16; k++) {
            float4 a4 = *(const float4*)&As[k][ty * 4];
            float4 b4 = *(const float4*)&Bs[k][tx * 4];
            float a[4] = {a4.x, a4.y, a4.z, a4.w};
            float b[4] = {b4.x, b4.y, b4.z, b4.w};
            #pragma unroll
            for (int r = 0; r < 4; r++)
                #pragma unroll
                for (int c = 0; c < 4; c++)
                    acc[r][c] += a[r] * b[c];
        }
    }
    const int j0 = col0 + tx * 4;
    const int which = j0 >> 11;
    const int hh = (j0 & 2047) >> 7;
    const int d0 = j0 & 127;
    const float bv0 = bias[j0 + 0], bv1 = bias[j0 + 1];
    const float bv2 = bias[j0 + 2], bv3 = bias[j0 + 3];
    #pragma unroll
    for (int r = 0; r < 4; r++) {
        const int grow = row0 + ty * 4 + r;
        float v0 = acc[r][0] + bv0, v1 = acc[r][1] + bv1;
        float v2 = acc[r][2] + bv2, v3 = acc[r][3] + bv3;
        if (which == 2) {
            const int pos = input_pos[grow];
            float4 o4 = make_float4(v0, v1, v2, v3);
            *(float4*)&vb[((size_t)hh * S + pos) * HD + d0] = o4;
        } else {
            const float* fc = &freqs[((size_t)grow * 64 + (d0 >> 1)) * 2];
            float c0 = fc[0], s0 = fc[1], c1 = fc[2], s1 = fc[3];
            float o0 = v0 * c0 - v1 * s0, o1 = v1 * c0 + v0 * s0;
            float o2 = v2 * c1 - v3 * s1, o3 = v3 * c1 + v2 * s1;
            float4 o4 = make_float4(o0, o1, o2, o3);
            if (which == 0) {
                *(float4*)&qb[((size_t)hh * S + grow) * HD + d0] = o4;
            } else {
                const int pos = input_pos[grow];
                *(float4*)&kb[((size_t)hh * S + pos) * HD + d0] = o4;
            }
        }
    }
}

#define BQ 64
#define ABK 32
#define QSTR 132
#define KVSTR 132
#define PSTR 68

__global__ __launch_bounds__(256) void attn_kernel(
    const float* __restrict__ qb, const float* __restrict__ kb,
    const float* __restrict__ vb, float* __restrict__ ctx)
{
    __shared__ float Qs[BQ * QSTR];
    __shared__ float KV[ABK * KVSTR];
    __shared__ float Psf[ABK * PSTR];

    const int pa = blockIdx.x;
    const int h  = blockIdx.y;
    const int t  = threadIdx.x;
    const int ty = t >> 4, tx = t & 15;
    const int i0  = ty * 4;
    const int j0  = tx * 2;
    const int dd0 = tx * 8;
    const int lr = t >> 3;
    const int lc = (t & 7) * 4;

    const float* kbase = kb + (size_t)h * S * HD;
    const float* vbase = vb + (size_t)h * S * HD;
    const float kSc = 0.08838834764831845f * 1.4426950408889634f;

    for (int ph = 0; ph < 2; ph++) {
        const int r = (ph == 0) ? pa : 31 - pa;
        const int q0 = r * BQ;
        const int ntiles = 2 * r + 2;

        #pragma unroll
        for (int pp = 0; pp < 2; pp++) {
            const int iq = lr + pp * 32;
            const float* src = qb + ((size_t)h * S + q0 + iq) * HD;
            #pragma unroll
            for (int ch = 0; ch < 4; ch++)
                *(float4*)&Qs[iq * QSTR + lc + ch * 32] =
                    *(const float4*)&src[lc + ch * 32];
        }

        float O[4][8] = {};
        float m[4], l[4];
        #pragma unroll
        for (int rr = 0; rr < 4; rr++) { m[rr] = -1e30f; l[rr] = 0.f; }

        float4 kpref[4];
        #pragma unroll
        for (int ch = 0; ch < 4; ch++)
            kpref[ch] = *(const float4*)&kbase[(size_t)lr * HD + lc + ch * 32];

        __syncthreads();

        for (int kt = 0; kt < ntiles; kt++) {
            const int k0 = kt * ABK;

            #pragma unroll
            for (int ch = 0; ch < 4; ch++)
                *(float4*)&KV[lr * KVSTR + lc + ch * 32] = kpref[ch];
            __syncthreads();

            float4 vpref[4];
            #pragma unroll
            for (int ch = 0; ch < 4; ch++)
                vpref[ch] = *(const float4*)&vbase[(size_t)(k0 + lr) * HD + lc + ch * 32];

            float acc[4][2] = {};
            #pragma unroll 4
            for (int d0 = 0; d0 < HD; d0 += 4) {
                float4 ka = *(const float4*)&KV[(j0 + 0) * KVSTR + d0];
                float4 kb4 = *(const float4*)&KV[(j0 + 1) * KVSTR + d0];
                #pragma unroll
                for (int rr = 0; rr < 4; rr++) {
                    float4 q4 = *(const float4*)&Qs[(i0 + rr) * QSTR + d0];
                    acc[rr][0] += q4.x * ka.x + q4.y * ka.y + q4.z * ka.z + q4.w * ka.w;
                    acc[rr][1] += q4.x * kb4.x + q4.y * kb4.y + q4.z * kb4.z + q4.w * kb4.w;
                }
            }

            const bool need_mask = (k0 + ABK - 1) > q0;
            float p[4][2], alpha[4];
            #pragma unroll
            for (int rr = 0; rr < 4; rr++) {
                float z0 = acc[rr][0] * kSc;
                float z1 = acc[rr][1] * kSc;
                if (need_mask) {
                    if (k0 + j0 + 0 > q0 + i0 + rr) z0 = -1e30f;
                    if (k0 + j0 + 1 > q0 + i0 + rr) z1 = -1e30f;
                }
                float rmax = fmaxf(z0, z1);
                #pragma unroll
                for (int off = 1; off < 16; off <<= 1)
                    rmax = fmaxf(rmax, __shfl_xor(rmax, off, 16));
                const float nm = fmaxf(m[rr], rmax);
                alpha[rr] = exp2f(m[rr] - nm);
                p[rr][0] = exp2f(z0 - nm);
                p[rr][1] = exp2f(z1 - nm);
                float ts = p[rr][0] + p[rr][1];
                #pragma unroll
                for (int off = 1; off < 16; off <<= 1)
                    ts += __shfl_xor(ts, off, 16);
                l[rr] = l[rr] * alpha[rr] + ts;
                m[rr] = nm;
            }
            __syncthreads();

            #pragma unroll
            for (int ch = 0; ch < 4; ch++)
                *(float4*)&KV[lr * KVSTR + lc + ch * 32] = vpref[ch];
            *(float4*)&Psf[(j0 + 0) * PSTR + i0] =
                make_float4(p[0][0], p[1][0], p[2][0], p[3][0]);
            *(float4*)&Psf[(j0 + 1) * PSTR + i0] =
                make_float4(p[0][1], p[1][1], p[2][1], p[3][1]);
            if (kt + 1 < ntiles) {
                #pragma unroll
                for (int ch = 0; ch < 4; ch++)
                    kpref[ch] = *(const float4*)&kbase[(size_t)(k0 + ABK + lr) * HD + lc + ch * 32];
            }
            __syncthreads();

            #pragma unroll
            for (int rr = 0; rr < 4; rr++)
                #pragma unroll
                for (int c = 0; c < 8; c++)
                    O[rr][c] *= alpha[rr];
            #pragma unroll 4
            for (int j = 0; j < ABK; j++) {
                float4 pj = *(const float4*)&Psf[j * PSTR + i0];
                float4 v0 = *(const float4*)&KV[j * KVSTR + dd0];
                float4 v1 = *(const float4*)&KV[j * KVSTR + dd0 + 4];
                const float pr[4] = {pj.x, pj.y, pj.z, pj.w};
                const float vv[8] = {v0.x, v0.y, v0.z, v0.w, v1.x, v1.y, v1.z, v1.w};
                #pragma unroll
                for (int rr = 0; rr < 4; rr++)
                    #pragma unroll
                    for (int c = 0; c < 8; c++)
                        O[rr][c] += pr[rr] * vv[c];
            }
            __syncthreads();
        }

        #pragma unroll
        for (int rr = 0; rr < 4; rr++) {
            const float inv = 1.0f / l[rr];
            const int qg = q0 + i0 + rr;
            float4 o0 = make_float4(O[rr][0] * inv, O[rr][1] * inv,
                                    O[rr][2] * inv, O[rr][3] * inv);
            float4 o1 = make_float4(O[rr][4] * inv, O[rr][5] * inv,
                                    O[rr][6] * inv, O[rr][7] * inv);
            float* dst = &ctx[((size_t)qg * H + h) * HD + dd0];
            *(float4*)&dst[0] = o0;
            *(float4*)&dst[4] = o1;
        }
        __syncthreads();
    }
}

__global__ __launch_bounds__(256) void gemm_dense_kernel(
    const float* __restrict__ A, const float* __restrict__ W,
    const float* __restrict__ bias, float* __restrict__ out)
{
    __shared__ float As[16][68];
    __shared__ float Bs[16][64];
    const int bx = blockIdx.x;
    const int by = blockIdx.y;
    const int tid = threadIdx.x;
    const int tx = tid & 15, ty = tid >> 4;
    const int row0 = by * 64, col0 = bx * 64;
    const int am = tid >> 2;
    const int ak = (tid & 3) * 4;
    const int bk = tid >> 4;
    const int bn = (tid & 15) * 4;
    float acc[4][4] = {};
    for (int k0 = 0; k0 < D; k0 += 16) {
        float4 av = *(const float4*)&A[(size_t)(row0 + am) * D + k0 + ak];
        float4 bv = *(const float4*)&W[(size_t)(k0 + bk) * D + col0 + bn];
        __syncthreads();
        As[ak + 0][am] = av.x; As[ak + 1][am] = av.y;
        As[ak + 2][am] = av.z; As[ak + 3][am] = av.w;
        *(float4*)&Bs[bk][bn] = bv;
        __syncthreads();
        #pragma unroll
        for (int k = 0; k < 16; k++) {
            float4 a4 = *(const float4*)&As[k][ty * 4];
            float4 b4 = *(const float4*)&Bs[k][tx * 4];
            float a[4] = {a4.x, a4.y, a4.z, a4.w};
            float b[4] = {b4.x, b4.y, b4.z, b4.w};
            #pragma unroll
            for (int r = 0; r < 4; r++)
                #pragma unroll
                for (int c = 0; c < 4; c++)
                    acc[r][c] += a[r] * b[c];
        }
    }
    const int j0 = col0 + tx * 4;
    const float bv0 = bias[j0 + 0], bv1 = bias[j0 + 1];
    const float bv2 = bias[j0 + 2], bv3 = bias[j0 + 3];
    #pragma unroll
    for (int r = 0; r < 4; r++) {
        const int grow = row0 + ty * 4 + r;
        float4 o4 = make_float4(acc[r][0] + bv0, acc[r][1] + bv1,
                                acc[r][2] + bv2, acc[r][3] + bv3);
        *(float4*)&out[(size_t)grow * D + j0] = o4;
    }
}

extern "C" void kernel_launch(void* const* d_in, const int* in_sizes, int n_in,
                              void* d_out, int out_size, void* d_ws, size_t ws_size,
                              hipStream_t stream) {
    const float* x      = (const float*)d_in[0];
    const float* freqs  = (const float*)d_in[1];
    const int*   pos    = (const int*)d_in[2];
    const float* Wqkv   = (const float*)d_in[3];
    const float* bqkv   = (const float*)d_in[4];
    const float* Wdense = (const float*)d_in[5];
    const float* bdense = (const float*)d_in[6];
    float* out = (float*)d_out;

    const size_t nSD = (size_t)S * D;   // 4 Mi elems
    const size_t nW1 = (size_t)D * N3;  // 12 Mi elems

    // mfma path ws (all bf16): 12 nSD-sized arrays + 2 nW1-sized = 144 MiB
    const size_t needed = (12 * nSD + 2 * nW1) * sizeof(ushort_t);

    if (ws_size >= needed) {
        ushort_t* qh   = (ushort_t*)d_ws;
        ushort_t* ql   = qh + nSD;
        ushort_t* kh   = ql + nSD;
        ushort_t* kl   = kh + nSD;
        ushort_t* vh   = kl + nSD;
        ushort_t* vl   = vh + nSD;
        ushort_t* ctxh = vl + nSD;
        ushort_t* ctxl = ctxh + nSD;
        ushort_t* xh   = ctxl + nSD;
        ushort_t* xl   = xh + nSD;
        ushort_t* Wth  = xl + nSD;
        ushort_t* Wtl  = Wth + nW1;
        ushort_t* Wdth = Wtl + nW1;
        ushort_t* Wdtl = Wdth + nSD;

        convert_split_kernel<<<nSD / 4 / 256, 256, 0, stream>>>(x, xh, xl);
        dim3 gt1(D / 32, N3 / 32);
        convert_split_t_kernel<<<gt1, 256, 0, stream>>>(Wqkv, Wth, Wtl, D, N3);
        dim3 gt2(D / 32, D / 32);
        convert_split_t_kernel<<<gt2, 256, 0, stream>>>(Wdense, Wdth, Wdtl, D, D);

        dim3 g1(N3 / 128, S / 128);
        gemm_qkv_mfma<<<g1, 256, 0, stream>>>(xh, xl, Wth, Wtl, bqkv, freqs,
                                              pos, qh, ql, kh, kl, vh, vl);
        dim3 g2(32, H);
        attn_mfma_kernel<<<g2, 256, 0, stream>>>(qh, ql, kh, kl, vh, vl,
                                                 ctxh, ctxl);
        dim3 g3(D / 128, S / 128);
        gemm_dense_mfma<<<g3, 256, 0, stream>>>(ctxh, ctxl, Wdth, Wdtl, bdense, out);
    } else {
        // fallback: R2 f32 path (needs only 64 MiB)
        float* qb  = (float*)d_ws;
        float* kb  = qb + (size_t)H * S * HD;
        float* vb  = kb + (size_t)H * S * HD;
        float* ctx = vb + (size_t)H * S * HD;
        dim3 g1(N3 / 64, S / 64);
        gemm_qkv_kernel<<<g1, 256, 0, stream>>>(x, Wqkv, bqkv, freqs, pos, qb, kb, vb);
        dim3 g2(16, H);
        attn_kernel<<<g2, 256, 0, stream>>>(qb, kb, vb, ctx);
        dim3 g3(D / 64, S / 64);
        gemm_dense_kernel<<<g3, 256, 0, stream>>>(ctx, Wdense, bdense, out);
    }
}

// Round 7
// 558.235 us; speedup vs baseline: 10.1604x; 1.0761x over previous
//
#include <hip/hip_runtime.h>

#define S 2048
#define D 2048
#define H 16
#define HD 128
#define N3 6144  // 3*D

typedef __attribute__((ext_vector_type(8))) short bf16x8;
typedef __attribute__((ext_vector_type(4))) float f32x4;
typedef unsigned short ushort_t;
typedef unsigned int uint_t;

// ---------------------------------------------------------------------------
// bf16 split helpers (round-to-nearest-even)
// ---------------------------------------------------------------------------
__device__ __forceinline__ ushort_t bf16_rne(float f) {
    uint_t u = __float_as_uint(f);
    u += 0x7fffu + ((u >> 16) & 1u);
    return (ushort_t)(u >> 16);
}
__device__ __forceinline__ float bf16_f32(ushort_t h) {
    return __uint_as_float(((uint_t)h) << 16);
}

// split f32 row-major -> hi/lo bf16 row-major (same layout)
__global__ __launch_bounds__(256) void convert_split_kernel(
    const float* __restrict__ in, ushort_t* __restrict__ hi,
    ushort_t* __restrict__ lo)
{
    const int i = blockIdx.x * 256 + threadIdx.x;  // per float4
    float4 v = ((const float4*)in)[i];
    ushort_t h0 = bf16_rne(v.x), h1 = bf16_rne(v.y);
    ushort_t h2 = bf16_rne(v.z), h3 = bf16_rne(v.w);
    ushort4 hv = make_ushort4(h0, h1, h2, h3);
    ushort4 lv = make_ushort4(bf16_rne(v.x - bf16_f32(h0)),
                              bf16_rne(v.y - bf16_f32(h1)),
                              bf16_rne(v.z - bf16_f32(h2)),
                              bf16_rne(v.w - bf16_f32(h3)));
    ((ushort4*)hi)[i] = hv;
    ((ushort4*)lo)[i] = lv;
}

// W [K][N] f32 -> Wt hi/lo [N][K] bf16 (transpose + split), 32x32 tiles.
// R7: ushort4 (8 B) stores instead of scalar ushort.
__global__ __launch_bounds__(256) void convert_split_t_kernel(
    const float* __restrict__ in, ushort_t* __restrict__ hi,
    ushort_t* __restrict__ lo, int Kdim, int Ndim)
{
    __shared__ float tile[32][33];
    const int k0 = blockIdx.x * 32, n0 = blockIdx.y * 32;
    const int tx = threadIdx.x & 31, ty = threadIdx.x >> 5;  // ty 0..7
    #pragma unroll
    for (int r = 0; r < 4; r++)
        tile[ty + r * 8][tx] = in[(size_t)(k0 + ty + r * 8) * Ndim + n0 + tx];
    __syncthreads();
    const int n  = threadIdx.x >> 3;        // 0..31 local col
    const int kc = (threadIdx.x & 7) * 4;   // 0..28 local k chunk
    const float v0 = tile[kc + 0][n], v1 = tile[kc + 1][n];
    const float v2 = tile[kc + 2][n], v3 = tile[kc + 3][n];
    const ushort_t h0 = bf16_rne(v0), h1 = bf16_rne(v1);
    const ushort_t h2 = bf16_rne(v2), h3 = bf16_rne(v3);
    const size_t off = (size_t)(n0 + n) * Kdim + k0 + kc;
    *(ushort4*)&hi[off] = make_ushort4(h0, h1, h2, h3);
    *(ushort4*)&lo[off] = make_ushort4(bf16_rne(v0 - bf16_f32(h0)),
                                       bf16_rne(v1 - bf16_f32(h1)),
                                       bf16_rne(v2 - bf16_f32(h2)),
                                       bf16_rne(v3 - bf16_f32(h3)));
}

// ---------------------------------------------------------------------------
// async global->LDS, 16 B per lane, wave-uniform LDS base (HW adds lane*16).
// ---------------------------------------------------------------------------
__device__ __forceinline__ void gload16(const ushort_t* g, ushort_t* l) {
    __builtin_amdgcn_global_load_lds(
        (const __attribute__((address_space(1))) unsigned int*)g,
        (__attribute__((address_space(3))) unsigned int*)l, 16, 0, 0);
}

// ---------------------------------------------------------------------------
// Split-bf16 MFMA GEMM core, R7: DOUBLE-BUFFERED staging (1 barrier/iter).
// 128x128 tile, BK=32, 4 waves 2x2, 3-term (Ah*Bh + Ah*Bl + Al*Bh).
// LDS: [2 bufs][4 streams][128*32] bf16 = 64 KB -> 2 blocks/CU. The vmcnt
// drain at each barrier now overlaps a full compute phase (~1000 cyc).
// ---------------------------------------------------------------------------
#define BK 32
#define TILE_ELEMS (128 * BK)

__device__ __forceinline__ void mm_core_split(
    const ushort_t* __restrict__ Agh, const ushort_t* __restrict__ Agl,
    const ushort_t* __restrict__ Bgh, const ushort_t* __restrict__ Bgl,
    const int K, ushort_t* lds, const int t, f32x4 (&acc)[4][4])
{
    const int lane = t & 63;
    const int wv   = t >> 6;
    const int lrow = lane >> 2;
    const int lk   = (lane & 3) * 8;
    const int quad = lane >> 4;
    const int lr   = lane & 15;
    const int wm   = (wv & 1) * 64;
    const int wn   = (wv >> 1) * 64;

    const int r0  = wv * 16;
    const int lo0 = r0 * BK;
    const int lo1 = (r0 + 64) * BK;

    auto stage = [&](int k0, int buf) {
        ushort_t* base = lds + buf * 4 * TILE_ELEMS;
        ushort_t* As_h = base;
        ushort_t* As_l = base + TILE_ELEMS;
        ushort_t* Bs_h = base + 2 * TILE_ELEMS;
        ushort_t* Bs_l = base + 3 * TILE_ELEMS;
        const size_t go0 = (size_t)(r0 + lrow) * K + k0 + lk;
        const size_t go1 = (size_t)(r0 + 64 + lrow) * K + k0 + lk;
        gload16(Agh + go0, As_h + lo0);
        gload16(Agh + go1, As_h + lo1);
        gload16(Agl + go0, As_l + lo0);
        gload16(Agl + go1, As_l + lo1);
        gload16(Bgh + go0, Bs_h + lo0);
        gload16(Bgh + go1, Bs_h + lo1);
        gload16(Bgl + go0, Bs_l + lo0);
        gload16(Bgl + go1, Bs_l + lo1);
    };

    stage(0, 0);

    const int niter = K / BK;
    for (int it = 0; it < niter; it++) {
        const int cur = it & 1;
        __syncthreads();  // drains vmcnt: tile it visible; buf cur^1 free

        if (it + 1 < niter) stage((it + 1) * BK, cur ^ 1);

        ushort_t* base = lds + cur * 4 * TILE_ELEMS;
        ushort_t* As_h = base;
        ushort_t* As_l = base + TILE_ELEMS;
        ushort_t* Bs_h = base + 2 * TILE_ELEMS;
        ushort_t* Bs_l = base + 3 * TILE_ELEMS;

        bf16x8 af_h[4], af_l[4], bf_h[4], bf_l[4];
        #pragma unroll
        for (int i = 0; i < 4; i++) {
            af_h[i] = *(const bf16x8*)&As_h[(wm + i * 16 + lr) * BK + quad * 8];
            af_l[i] = *(const bf16x8*)&As_l[(wm + i * 16 + lr) * BK + quad * 8];
            bf_h[i] = *(const bf16x8*)&Bs_h[(wn + i * 16 + lr) * BK + quad * 8];
            bf_l[i] = *(const bf16x8*)&Bs_l[(wn + i * 16 + lr) * BK + quad * 8];
        }
        #pragma unroll
        for (int mt = 0; mt < 4; mt++)
            #pragma unroll
            for (int nt = 0; nt < 4; nt++) {
                acc[mt][nt] = __builtin_amdgcn_mfma_f32_16x16x32_bf16(
                    af_h[mt], bf_h[nt], acc[mt][nt], 0, 0, 0);
                acc[mt][nt] = __builtin_amdgcn_mfma_f32_16x16x32_bf16(
                    af_h[mt], bf_l[nt], acc[mt][nt], 0, 0, 0);
                acc[mt][nt] = __builtin_amdgcn_mfma_f32_16x16x32_bf16(
                    af_l[mt], bf_h[nt], acc[mt][nt], 0, 0, 0);
            }
    }
}

// ---------------------------------------------------------------------------
// QKV GEMM (MFMA) with split-bf16 outputs (epilogue unchanged from R6).
// ---------------------------------------------------------------------------
__global__ __launch_bounds__(256) void gemm_qkv_mfma(
    const ushort_t* __restrict__ xh, const ushort_t* __restrict__ xl,
    const ushort_t* __restrict__ Wth, const ushort_t* __restrict__ Wtl,
    const float* __restrict__ bias, const float* __restrict__ freqs,
    const int* __restrict__ input_pos,
    ushort_t* __restrict__ qhg, ushort_t* __restrict__ qlg,
    ushort_t* __restrict__ khg, ushort_t* __restrict__ klg,
    ushort_t* __restrict__ vhg, ushort_t* __restrict__ vlg)
{
    __shared__ ushort_t lds[2 * 4 * TILE_ELEMS];   // 64 KB
    const int t = threadIdx.x;
    const int col0 = blockIdx.x * 128;
    const int row0 = blockIdx.y * 128;

    f32x4 acc[4][4] = {};
    mm_core_split(xh + (size_t)row0 * D, xl + (size_t)row0 * D,
                  Wth + (size_t)col0 * D, Wtl + (size_t)col0 * D,
                  D, lds, t, acc);

    const int lane = t & 63;
    const int quad = lane >> 4;
    const int lr   = lane & 15;
    const int wm = ((t >> 6) & 1) * 64;
    const int wn = ((t >> 6) >> 1) * 64;

    const int which = col0 >> 11;           // 0=q 1=k 2=v
    const int hh = (col0 & 2047) >> 7;

    if (which == 2) {
        ushort_t* vh_b = vhg + (size_t)hh * HD * S;
        ushort_t* vl_b = vlg + (size_t)hh * HD * S;
        #pragma unroll
        for (int nt = 0; nt < 4; nt++) {
            const int d = wn + nt * 16 + lr;
            const float bsc = bias[col0 + d];
            #pragma unroll
            for (int mt = 0; mt < 4; mt++) {
                #pragma unroll
                for (int reg = 0; reg < 4; reg++) {
                    const int m = row0 + wm + mt * 16 + quad * 4 + reg;
                    const float v = acc[mt][nt][reg] + bsc;
                    const ushort_t hv = bf16_rne(v);
                    const ushort_t lv = bf16_rne(v - bf16_f32(hv));
                    const int pos = input_pos[m];
                    vh_b[(size_t)d * S + pos] = hv;
                    vl_b[(size_t)d * S + pos] = lv;
                }
            }
        }
    } else {
        ushort_t* oh_b = ((which == 0) ? qhg : khg) + (size_t)hh * S * HD;
        ushort_t* ol_b = ((which == 0) ? qlg : klg) + (size_t)hh * S * HD;
        #pragma unroll
        for (int nt = 0; nt < 4; nt++) {
            const int d = wn + nt * 16 + lr;
            const float bsc = bias[col0 + d];
            #pragma unroll
            for (int mt = 0; mt < 4; mt++) {
                #pragma unroll
                for (int reg = 0; reg < 4; reg++) {
                    const int m = row0 + wm + mt * 16 + quad * 4 + reg;
                    const float v = acc[mt][nt][reg] + bsc;
                    const float* fc = &freqs[((size_t)m * 64 + (d >> 1)) * 2];
                    const float c = fc[0], s = fc[1];
                    const float p = __shfl_xor(v, 1);
                    const float o = (d & 1) ? (v * c + p * s) : (v * c - p * s);
                    const ushort_t hv = bf16_rne(o);
                    const ushort_t lv = bf16_rne(o - bf16_f32(hv));
                    const int hp = __shfl_xor((int)hv, 1);
                    const int lp = __shfl_xor((int)lv, 1);
                    if (!(d & 1)) {
                        const int srow = (which == 0) ? m : input_pos[m];
                        *(uint_t*)&oh_b[(size_t)srow * HD + d] =
                            (uint_t)hv | ((uint_t)hp << 16);
                        *(uint_t*)&ol_b[(size_t)srow * HD + d] =
                            (uint_t)lv | ((uint_t)lp << 16);
                    }
                }
            }
        }
    }
}

// ---------------------------------------------------------------------------
// MFMA flash attention (unchanged from R6 — verified win).
// ---------------------------------------------------------------------------
__global__ __launch_bounds__(256, 2) void attn_mfma_kernel(
    const ushort_t* __restrict__ qhg, const ushort_t* __restrict__ qlg,
    const ushort_t* __restrict__ khg, const ushort_t* __restrict__ klg,
    const ushort_t* __restrict__ vhg, const ushort_t* __restrict__ vlg,
    ushort_t* __restrict__ ctxh, ushort_t* __restrict__ ctxl)
{
    __shared__ ushort_t Khs[2][4096];   // [buf][ks*1024 + key*32 + d8]
    __shared__ ushort_t Kls[2][4096];
    __shared__ ushort_t Vhs[2][4096];   // [buf][dim*32 + key8]
    __shared__ ushort_t Vls[2][4096];
    __shared__ ushort_t Ps[64 * 32];

    const int h = blockIdx.y;
    const int r = (h & 8) ? blockIdx.x : (31 - blockIdx.x);
    const int q0 = r * 64;
    const int ntiles = 2 * r + 2;
    const int t = threadIdx.x;
    const int w = t >> 6, lane = t & 63;
    const int lr = lane & 15, quad = lane >> 4;

    const size_t qrow = (size_t)h * S + q0 + w * 16 + lr;
    bf16x8 qf_h[4], qf_l[4];
    #pragma unroll
    for (int ks = 0; ks < 4; ks++) {
        qf_h[ks] = *(const bf16x8*)&qhg[qrow * HD + ks * 32 + quad * 8];
        qf_l[ks] = *(const bf16x8*)&qlg[qrow * HD + ks * 32 + quad * 8];
    }

    const ushort_t* kh_b = khg + (size_t)h * S * HD;
    const ushort_t* kl_b = klg + (size_t)h * S * HD;
    const ushort_t* vh_b = vhg + (size_t)h * HD * S;
    const ushort_t* vl_b = vlg + (size_t)h * HD * S;

    const int keyq = lane >> 2;   // 0..15
    const int sub  = lane & 3;    // 16B chunk index

    auto stage = [&](int kt, int buf) {
        const int k0 = kt * 32;
        #pragma unroll
        for (int hf = 0; hf < 2; hf++) {
            const size_t ksrc = (size_t)(k0 + hf * 16 + keyq) * HD + w * 32 + sub * 8;
            gload16(kh_b + ksrc, &Khs[buf][w * 1024 + hf * 512]);
            gload16(kl_b + ksrc, &Kls[buf][w * 1024 + hf * 512]);
            const int dim = w * 32 + hf * 16 + keyq;
            const size_t vsrc = (size_t)dim * S + k0 + sub * 8;
            gload16(vh_b + vsrc, &Vhs[buf][(w * 32 + hf * 16) * 32]);
            gload16(vl_b + vsrc, &Vls[buf][(w * 32 + hf * 16) * 32]);
        }
    };

    f32x4 O[8] = {};
    float mrow[4], lrow[4];
    #pragma unroll
    for (int rr = 0; rr < 4; rr++) { mrow[rr] = -1e30f; lrow[rr] = 0.f; }

    const float kSc = 0.08838834764831845f * 1.4426950408889634f; // scale*log2e

    stage(0, 0);

    for (int kt = 0; kt < ntiles; kt++) {
        const int k0 = kt * 32;
        const int cur = kt & 1;
        __syncthreads();  // drains vmcnt -> tile kt visible; buf cur^1 free

        if (kt + 1 < ntiles) stage(kt + 1, cur ^ 1);

        f32x4 sa[2];
        #pragma unroll
        for (int nt = 0; nt < 2; nt++) {
            f32x4 s = {0.f, 0.f, 0.f, 0.f};
            #pragma unroll
            for (int ks = 0; ks < 4; ks++) {
                bf16x8 kf_h = *(const bf16x8*)&Khs[cur][ks * 1024 + (nt * 16 + lr) * 32 + quad * 8];
                bf16x8 kf_l = *(const bf16x8*)&Kls[cur][ks * 1024 + (nt * 16 + lr) * 32 + quad * 8];
                s = __builtin_amdgcn_mfma_f32_16x16x32_bf16(qf_h[ks], kf_h, s, 0, 0, 0);
                s = __builtin_amdgcn_mfma_f32_16x16x32_bf16(qf_l[ks], kf_h, s, 0, 0, 0);
                s = __builtin_amdgcn_mfma_f32_16x16x32_bf16(qf_h[ks], kf_l, s, 0, 0, 0);
            }
            sa[nt] = s;
        }

        const int rowbase = q0 + w * 16 + quad * 4;
        const bool need_mask = (k0 + 31) > (q0 + w * 16);
        float alpha[4], pv0[4], pv1[4];
        #pragma unroll
        for (int rr = 0; rr < 4; rr++) {
            float z0 = sa[0][rr] * kSc;
            float z1 = sa[1][rr] * kSc;
            if (need_mask) {
                const int rowg = rowbase + rr;
                if (k0 + lr > rowg)      z0 = -1e30f;
                if (k0 + 16 + lr > rowg) z1 = -1e30f;
            }
            float rm = fmaxf(z0, z1);
            #pragma unroll
            for (int off = 1; off < 16; off <<= 1)
                rm = fmaxf(rm, __shfl_xor(rm, off));
            const float nm = fmaxf(mrow[rr], rm);
            const float al = exp2f(mrow[rr] - nm);
            const float p0 = exp2f(z0 - nm);
            const float p1 = exp2f(z1 - nm);
            float ts = p0 + p1;
            #pragma unroll
            for (int off = 1; off < 16; off <<= 1)
                ts += __shfl_xor(ts, off);
            lrow[rr] = lrow[rr] * al + ts;
            mrow[rr] = nm;
            alpha[rr] = al;
            pv0[rr] = p0;
            pv1[rr] = p1;
        }

        #pragma unroll
        for (int rr = 0; rr < 4; rr++) {
            const int prow = (w * 16 + quad * 4 + rr) * 32;
            Ps[prow + lr]      = bf16_rne(pv0[rr]);
            Ps[prow + 16 + lr] = bf16_rne(pv1[rr]);
        }
        // no barrier: each wave reads only its own P rows (lgkmcnt orders)

        #pragma unroll
        for (int nt = 0; nt < 8; nt++)
            #pragma unroll
            for (int rr = 0; rr < 4; rr++)
                O[nt][rr] *= alpha[rr];
        const bf16x8 pf = *(const bf16x8*)&Ps[(w * 16 + lr) * 32 + quad * 8];
        #pragma unroll
        for (int nt = 0; nt < 8; nt++) {
            bf16x8 vf_h = *(const bf16x8*)&Vhs[cur][(nt * 16 + lr) * 32 + quad * 8];
            bf16x8 vf_l = *(const bf16x8*)&Vls[cur][(nt * 16 + lr) * 32 + quad * 8];
            O[nt] = __builtin_amdgcn_mfma_f32_16x16x32_bf16(pf, vf_h, O[nt], 0, 0, 0);
            O[nt] = __builtin_amdgcn_mfma_f32_16x16x32_bf16(pf, vf_l, O[nt], 0, 0, 0);
        }
    }

    #pragma unroll
    for (int rr = 0; rr < 4; rr++) {
        const float inv = 1.0f / lrow[rr];
        const int qg = q0 + w * 16 + quad * 4 + rr;
        const size_t roff = (size_t)qg * D + h * HD;
        #pragma unroll
        for (int nt = 0; nt < 8; nt++) {
            const float o = O[nt][rr] * inv;
            const ushort_t hv = bf16_rne(o);
            const ushort_t lv = bf16_rne(o - bf16_f32(hv));
            const int hp = __shfl_xor((int)hv, 1);
            const int lp = __shfl_xor((int)lv, 1);
            if (!(lr & 1)) {
                *(uint_t*)&ctxh[roff + nt * 16 + lr] = (uint_t)hv | ((uint_t)hp << 16);
                *(uint_t*)&ctxl[roff + nt * 16 + lr] = (uint_t)lv | ((uint_t)lp << 16);
            }
        }
    }
}

// ---------------------------------------------------------------------------
// Dense GEMM (MFMA, dbuf core): out = ctx @ Wdense + b
// ---------------------------------------------------------------------------
__global__ __launch_bounds__(256) void gemm_dense_mfma(
    const ushort_t* __restrict__ Ah, const ushort_t* __restrict__ Al,
    const ushort_t* __restrict__ Wth, const ushort_t* __restrict__ Wtl,
    const float* __restrict__ bias, float* __restrict__ out)
{
    __shared__ ushort_t lds[2 * 4 * TILE_ELEMS];   // 64 KB
    const int t = threadIdx.x;
    const int col0 = blockIdx.x * 128;
    const int row0 = blockIdx.y * 128;

    f32x4 acc[4][4] = {};
    mm_core_split(Ah + (size_t)row0 * D, Al + (size_t)row0 * D,
                  Wth + (size_t)col0 * D, Wtl + (size_t)col0 * D,
                  D, lds, t, acc);

    const int lane = t & 63;
    const int quad = lane >> 4;
    const int lr   = lane & 15;
    const int wm = ((t >> 6) & 1) * 64;
    const int wn = ((t >> 6) >> 1) * 64;

    #pragma unroll
    for (int nt = 0; nt < 4; nt++) {
        const int n = col0 + wn + nt * 16 + lr;
        const float bsc = bias[n];
        #pragma unroll
        for (int mt = 0; mt < 4; mt++) {
            #pragma unroll
            for (int reg = 0; reg < 4; reg++) {
                const int m = row0 + wm + mt * 16 + quad * 4 + reg;
                const float o = acc[mt][nt][reg] + bsc;
                const float po = __shfl_xor(o, 1);
                if (!(n & 1))
                    *(float2*)&out[(size_t)m * D + n] = make_float2(o, po);
            }
        }
    }
}

// ---------------------------------------------------------------------------
// Fallback f32 path (R2, known-good) for small workspace.
// ---------------------------------------------------------------------------
__global__ __launch_bounds__(256) void gemm_qkv_kernel(
    const float* __restrict__ x, const float* __restrict__ W,
    const float* __restrict__ bias, const float* __restrict__ freqs,
    const int* __restrict__ input_pos,
    float* __restrict__ qb, float* __restrict__ kb, float* __restrict__ vb)
{
    __shared__ float As[16][68];
    __shared__ float Bs[16][64];
    const int bx = blockIdx.x;
    const int by = blockIdx.y;
    const int tid = threadIdx.x;
    const int tx = tid & 15, ty = tid >> 4;
    const int row0 = by * 64, col0 = bx * 64;
    const int am = tid >> 2;
    const int ak = (tid & 3) * 4;
    const int bk = tid >> 4;
    const int bn = (tid & 15) * 4;
    float acc[4][4] = {};
    for (int k0 = 0; k0 < D; k0 += 16) {
        float4 av = *(const float4*)&x[(size_t)(row0 + am) * D + k0 + ak];
        float4 bv = *(const float4*)&W[(size_t)(k0 + bk) * N3 + col0 + bn];
        __syncthreads();
        As[ak + 0][am] = av.x; As[ak + 1][am] = av.y;
        As[ak + 2][am] = av.z; As[ak + 3][am] = av.w;
        *(float4*)&Bs[bk][bn] = bv;
        __syncthreads();
        #pragma unroll
        for (int k = 0; k < 16; k++) {
            float4 a4 = *(const float4*)&As[k][ty * 4];
            float4 b4 = *(const float4*)&Bs[k][tx * 4];
            float a[4] = {a4.x, a4.y, a4.z, a4.w};
            float b[4] = {b4.x, b4.y, b4.z, b4.w};
            #pragma unroll
            for (int r = 0; r < 4; r++)
                #pragma unroll
                for (int c = 0; c < 4; c++)
                    acc[r][c] += a[r] * b[c];
        }
    }
    const int j0 = col0 + tx * 4;
    const int which = j0 >> 11;
    const int hh = (j0 & 2047) >> 7;
    const int d0 = j0 & 127;
    const float bv0 = bias[j0 + 0], bv1 = bias[j0 + 1];
    const float bv2 = bias[j0 + 2], bv3 = bias[j0 + 3];
    #pragma unroll
    for (int r = 0; r < 4; r++) {
        const int grow = row0 + ty * 4 + r;
        float v0 = acc[r][0] + bv0, v1 = acc[r][1] + bv1;
        float v2 = acc[r][2] + bv2, v3 = acc[r][3] + bv3;
        if (which == 2) {
            const int pos = input_pos[grow];
            float4 o4 = make_float4(v0, v1, v2, v3);
            *(float4*)&vb[((size_t)hh * S + pos) * HD + d0] = o4;
        } else {
            const float* fc = &freqs[((size_t)grow * 64 + (d0 >> 1)) * 2];
            float c0 = fc[0], s0 = fc[1], c1 = fc[2], s1 = fc[3];
            float o0 = v0 * c0 - v1 * s0, o1 = v1 * c0 + v0 * s0;
            float o2 = v2 * c1 - v3 * s1, o3 = v3 * c1 + v2 * s1;
            float4 o4 = make_float4(o0, o1, o2, o3);
            if (which == 0) {
                *(float4*)&qb[((size_t)hh * S + grow) * HD + d0] = o4;
            } else {
                const int pos = input_pos[grow];
                *(float4*)&kb[((size_t)hh * S + pos) * HD + d0] = o4;
            }
        }
    }
}

#define BQ 64
#define ABK 32
#define QSTR 132
#define KVSTR 132
#define PSTR 68

__global__ __launch_bounds__(256) void attn_kernel(
    const float* __restrict__ qb, const float* __restrict__ kb,
    const float* __restrict__ vb, float* __restrict__ ctx)
{
    __shared__ float Qs[BQ * QSTR];
    __shared__ float KV[ABK * KVSTR];
    __shared__ float Psf[ABK * PSTR];

    const int pa = blockIdx.x;
    const int h  = blockIdx.y;
    const int t  = threadIdx.x;
    const int ty = t >> 4, tx = t & 15;
    const int i0  = ty * 4;
    const int j0  = tx * 2;
    const int dd0 = tx * 8;
    const int lr = t >> 3;
    const int lc = (t & 7) * 4;

    const float* kbase = kb + (size_t)h * S * HD;
    const float* vbase = vb + (size_t)h * S * HD;
    const float kSc = 0.08838834764831845f * 1.4426950408889634f;

    for (int ph = 0; ph < 2; ph++) {
        const int r = (ph == 0) ? pa : 31 - pa;
        const int q0 = r * BQ;
        const int ntiles = 2 * r + 2;

        #pragma unroll
        for (int pp = 0; pp < 2; pp++) {
            const int iq = lr + pp * 32;
            const float* src = qb + ((size_t)h * S + q0 + iq) * HD;
            #pragma unroll
            for (int ch = 0; ch < 4; ch++)
                *(float4*)&Qs[iq * QSTR + lc + ch * 32] =
                    *(const float4*)&src[lc + ch * 32];
        }

        float O[4][8] = {};
        float m[4], l[4];
        #pragma unroll
        for (int rr = 0; rr < 4; rr++) { m[rr] = -1e30f; l[rr] = 0.f; }

        float4 kpref[4];
        #pragma unroll
        for (int ch = 0; ch < 4; ch++)
            kpref[ch] = *(const float4*)&kbase[(size_t)lr * HD + lc + ch * 32];

        __syncthreads();

        for (int kt = 0; kt < ntiles; kt++) {
            const int k0 = kt * ABK;

            #pragma unroll
            for (int ch = 0; ch < 4; ch++)
                *(float4*)&KV[lr * KVSTR + lc + ch * 32] = kpref[ch];
            __syncthreads();

            float4 vpref[4];
            #pragma unroll
            for (int ch = 0; ch < 4; ch++)
                vpref[ch] = *(const float4*)&vbase[(size_t)(k0 + lr) * HD + lc + ch * 32];

            float acc[4][2] = {};
            #pragma unroll 4
            for (int d0 = 0; d0 < HD; d0 += 4) {
                float4 ka = *(const float4*)&KV[(j0 + 0) * KVSTR + d0];
                float4 kb4 = *(const float4*)&KV[(j0 + 1) * KVSTR + d0];
                #pragma unroll
                for (int rr = 0; rr < 4; rr++) {
                    float4 q4 = *(const float4*)&Qs[(i0 + rr) * QSTR + d0];
                    acc[rr][0] += q4.x * ka.x + q4.y * ka.y + q4.z * ka.z + q4.w * ka.w;
                    acc[rr][1] += q4.x * kb4.x + q4.y * kb4.y + q4.z * kb4.z + q4.w * kb4.w;
                }
            }

            const bool need_mask = (k0 + ABK - 1) > q0;
            float p[4][2], alpha[4];
            #pragma unroll
            for (int rr = 0; rr < 4; rr++) {
                float z0 = acc[rr][0] * kSc;
                float z1 = acc[rr][1] * kSc;
                if (need_mask) {
                    if (k0 + j0 + 0 > q0 + i0 + rr) z0 = -1e30f;
                    if (k0 + j0 + 1 > q0 + i0 + rr) z1 = -1e30f;
                }
                float rmax = fmaxf(z0, z1);
                #pragma unroll
                for (int off = 1; off < 16; off <<= 1)
                    rmax = fmaxf(rmax, __shfl_xor(rmax, off, 16));
                const float nm = fmaxf(m[rr], rmax);
                alpha[rr] = exp2f(m[rr] - nm);
                p[rr][0] = exp2f(z0 - nm);
                p[rr][1] = exp2f(z1 - nm);
                float ts = p[rr][0] + p[rr][1];
                #pragma unroll
                for (int off = 1; off < 16; off <<= 1)
                    ts += __shfl_xor(ts, off, 16);
                l[rr] = l[rr] * alpha[rr] + ts;
                m[rr] = nm;
            }
            __syncthreads();

            #pragma unroll
            for (int ch = 0; ch < 4; ch++)
                *(float4*)&KV[lr * KVSTR + lc + ch * 32] = vpref[ch];
            *(float4*)&Psf[(j0 + 0) * PSTR + i0] =
                make_float4(p[0][0], p[1][0], p[2][0], p[3][0]);
            *(float4*)&Psf[(j0 + 1) * PSTR + i0] =
                make_float4(p[0][1], p[1][1], p[2][1], p[3][1]);
            if (kt + 1 < ntiles) {
                #pragma unroll
                for (int ch = 0; ch < 4; ch++)
                    kpref[ch] = *(const float4*)&kbase[(size_t)(k0 + ABK + lr) * HD + lc + ch * 32];
            }
            __syncthreads();

            #pragma unroll
            for (int rr = 0; rr < 4; rr++)
                #pragma unroll
                for (int c = 0; c < 8; c++)
                    O[rr][c] *= alpha[rr];
            #pragma unroll 4
            for (int j = 0; j < ABK; j++) {
                float4 pj = *(const float4*)&Psf[j * PSTR + i0];
                float4 v0 = *(const float4*)&KV[j * KVSTR + dd0];
                float4 v1 = *(const float4*)&KV[j * KVSTR + dd0 + 4];
                const float pr[4] = {pj.x, pj.y, pj.z, pj.w};
                const float vv[8] = {v0.x, v0.y, v0.z, v0.w, v1.x, v1.y, v1.z, v1.w};
                #pragma unroll
                for (int rr = 0; rr < 4; rr++)
                    #pragma unroll
                    for (int c = 0; c < 8; c++)
                        O[rr][c] += pr[rr] * vv[c];
            }
            __syncthreads();
        }

        #pragma unroll
        for (int rr = 0; rr < 4; rr++) {
            const float inv = 1.0f / l[rr];
            const int qg = q0 + i0 + rr;
            float4 o0 = make_float4(O[rr][0] * inv, O[rr][1] * inv,
                                    O[rr][2] * inv, O[rr][3] * inv);
            float4 o1 = make_float4(O[rr][4] * inv, O[rr][5] * inv,
                                    O[rr][6] * inv, O[rr][7] * inv);
            float* dst = &ctx[((size_t)qg * H + h) * HD + dd0];
            *(float4*)&dst[0] = o0;
            *(float4*)&dst[4] = o1;
        }
        __syncthreads();
    }
}

__global__ __launch_bounds__(256) void gemm_dense_kernel(
    const float* __restrict__ A, const float* __restrict__ W,
    const float* __restrict__ bias, float* __restrict__ out)
{
    __shared__ float As[16][68];
    __shared__ float Bs[16][64];
    const int bx = blockIdx.x;
    const int by = blockIdx.y;
    const int tid = threadIdx.x;
    const int tx = tid & 15, ty = tid >> 4;
    const int row0 = by * 64, col0 = bx * 64;
    const int am = tid >> 2;
    const int ak = (tid & 3) * 4;
    const int bk = tid >> 4;
    const int bn = (tid & 15) * 4;
    float acc[4][4] = {};
    for (int k0 = 0; k0 < D; k0 += 16) {
        float4 av = *(const float4*)&A[(size_t)(row0 + am) * D + k0 + ak];
        float4 bv = *(const float4*)&W[(size_t)(k0 + bk) * D + col0 + bn];
        __syncthreads();
        As[ak + 0][am] = av.x; As[ak + 1][am] = av.y;
        As[ak + 2][am] = av.z; As[ak + 3][am] = av.w;
        *(float4*)&Bs[bk][bn] = bv;
        __syncthreads();
        #pragma unroll
        for (int k = 0; k < 16; k++) {
            float4 a4 = *(const float4*)&As[k][ty * 4];
            float4 b4 = *(const float4*)&Bs[k][tx * 4];
            float a[4] = {a4.x, a4.y, a4.z, a4.w};
            float b[4] = {b4.x, b4.y, b4.z, b4.w};
            #pragma unroll
            for (int r = 0; r < 4; r++)
                #pragma unroll
                for (int c = 0; c < 4; c++)
                    acc[r][c] += a[r] * b[c];
        }
    }
    const int j0 = col0 + tx * 4;
    const float bv0 = bias[j0 + 0], bv1 = bias[j0 + 1];
    const float bv2 = bias[j0 + 2], bv3 = bias[j0 + 3];
    #pragma unroll
    for (int r = 0; r < 4; r++) {
        const int grow = row0 + ty * 4 + r;
        float4 o4 = make_float4(acc[r][0] + bv0, acc[r][1] + bv1,
                                acc[r][2] + bv2, acc[r][3] + bv3);
        *(float4*)&out[(size_t)grow * D + j0] = o4;
    }
}

extern "C" void kernel_launch(void* const* d_in, const int* in_sizes, int n_in,
                              void* d_out, int out_size, void* d_ws, size_t ws_size,
                              hipStream_t stream) {
    const float* x      = (const float*)d_in[0];
    const float* freqs  = (const float*)d_in[1];
    const int*   pos    = (const int*)d_in[2];
    const float* Wqkv   = (const float*)d_in[3];
    const float* bqkv   = (const float*)d_in[4];
    const float* Wdense = (const float*)d_in[5];
    const float* bdense = (const float*)d_in[6];
    float* out = (float*)d_out;

    const size_t nSD = (size_t)S * D;   // 4 Mi elems
    const size_t nW1 = (size_t)D * N3;  // 12 Mi elems

    // mfma path ws (all bf16): 12 nSD-sized arrays + 2 nW1-sized = 144 MiB
    const size_t needed = (12 * nSD + 2 * nW1) * sizeof(ushort_t);

    if (ws_size >= needed) {
        ushort_t* qh   = (ushort_t*)d_ws;
        ushort_t* ql   = qh + nSD;
        ushort_t* kh   = ql + nSD;
        ushort_t* kl   = kh + nSD;
        ushort_t* vh   = kl + nSD;
        ushort_t* vl   = vh + nSD;
        ushort_t* ctxh = vl + nSD;
        ushort_t* ctxl = ctxh + nSD;
        ushort_t* xh   = ctxl + nSD;
        ushort_t* xl   = xh + nSD;
        ushort_t* Wth  = xl + nSD;
        ushort_t* Wtl  = Wth + nW1;
        ushort_t* Wdth = Wtl + nW1;
        ushort_t* Wdtl = Wdth + nSD;

        convert_split_kernel<<<nSD / 4 / 256, 256, 0, stream>>>(x, xh, xl);
        dim3 gt1(D / 32, N3 / 32);
        convert_split_t_kernel<<<gt1, 256, 0, stream>>>(Wqkv, Wth, Wtl, D, N3);
        dim3 gt2(D / 32, D / 32);
        convert_split_t_kernel<<<gt2, 256, 0, stream>>>(Wdense, Wdth, Wdtl, D, D);

        dim3 g1(N3 / 128, S / 128);
        gemm_qkv_mfma<<<g1, 256, 0, stream>>>(xh, xl, Wth, Wtl, bqkv, freqs,
                                              pos, qh, ql, kh, kl, vh, vl);
        dim3 g2(32, H);
        attn_mfma_kernel<<<g2, 256, 0, stream>>>(qh, ql, kh, kl, vh, vl,
                                                 ctxh, ctxl);
        dim3 g3(D / 128, S / 128);
        gemm_dense_mfma<<<g3, 256, 0, stream>>>(ctxh, ctxl, Wdth, Wdtl, bdense, out);
    } else {
        // fallback: R2 f32 path (needs only 64 MiB)
        float* qb  = (float*)d_ws;
        float* kb  = qb + (size_t)H * S * HD;
        float* vb  = kb + (size_t)H * S * HD;
        float* ctx = vb + (size_t)H * S * HD;
        dim3 g1(N3 / 64, S / 64);
        gemm_qkv_kernel<<<g1, 256, 0, stream>>>(x, Wqkv, bqkv, freqs, pos, qb, kb, vb);
        dim3 g2(16, H);
        attn_kernel<<<g2, 256, 0, stream>>>(qb, kb, vb, ctx);
        dim3 g3(D / 64, S / 64);
        gemm_dense_kernel<<<g3, 256, 0, stream>>>(ctx, Wdense, bdense, out);
    }
}